// Round 5
// baseline (328.654 us; speedup 1.0000x reference)
//
#include <hip/hip_runtime.h>
#include <hip/hip_bf16.h>

#define B_   2
#define S_   2048
#define HID_ 2048
#define H_   16
#define KVH_ 4
#define D_   128
#define M_   4096
#define NQKV 3072

typedef __attribute__((ext_vector_type(8))) short bf16x8;    // 8 bf16 = 4 VGPR
typedef __attribute__((ext_vector_type(4))) float f32x4;
typedef const __attribute__((address_space(1))) unsigned int* gas_p;
typedef __attribute__((address_space(3))) unsigned int* las_p;

__device__ __forceinline__ unsigned short f2b(float f) {
    __hip_bfloat16 h = __float2bfloat16(f);
    return *reinterpret_cast<unsigned short*>(&h);
}
__device__ __forceinline__ float b2f(unsigned short u) {
    __hip_bfloat16 h;
    *reinterpret_cast<unsigned short*>(&h) = u;
    return __bfloat162float(h);
}

// ---------- convert x: fp32 -> bf16 ----------------------------------------
__global__ __launch_bounds__(256)
void convert_x(const float* __restrict__ x, unsigned short* __restrict__ xb) {
    int i = (blockIdx.x * 256 + threadIdx.x) * 4;
    float4 v = *(const float4*)(x + i);
    ushort4 o;
    o.x = f2b(v.x); o.y = f2b(v.y); o.z = f2b(v.z); o.w = f2b(v.w);
    *(ushort4*)(xb + i) = o;
}

// ---------- all four weight converts in one launch (z selects matrix) ------
__global__ __launch_bounds__(256)
void convert_w_all(const float* __restrict__ wq, const float* __restrict__ wk,
                   const float* __restrict__ wv, const float* __restrict__ wo,
                   unsigned short* __restrict__ wqkvT,
                   unsigned short* __restrict__ woT) {
    __shared__ float tile[32][33];
    int z = blockIdx.z;
    const float* w; int N, nbase; unsigned short* dst;
    if (z == 0)      { w = wq; N = 2048; nbase = 0;    dst = wqkvT; }
    else if (z == 1) { w = wk; N = 512;  nbase = 2048; dst = wqkvT; }
    else if (z == 2) { w = wv; N = 512;  nbase = 2560; dst = wqkvT; }
    else             { w = wo; N = 2048; nbase = 0;    dst = woT; }
    int n0 = blockIdx.x * 32, k0 = blockIdx.y * 32;
    if (n0 >= N) return;
    int tx = threadIdx.x & 31, ty = threadIdx.x >> 5;
    #pragma unroll
    for (int j = 0; j < 4; j++)
        tile[ty + j*8][tx] = w[(size_t)(k0 + ty + j*8) * N + n0 + tx];
    __syncthreads();
    #pragma unroll
    for (int j = 0; j < 4; j++)
        dst[(size_t)(nbase + n0 + ty + j*8) * 2048 + k0 + tx] = f2b(tile[tx][ty + j*8]);
}

// ---------- shared 8-phase machinery ---------------------------------------
#define BAR    asm volatile("s_barrier" ::: "memory")
#define GATE2  asm volatile("s_waitcnt vmcnt(2)" ::: "memory")
#define GATE4  asm volatile("s_waitcnt vmcnt(4)" ::: "memory")
#define GATE6  asm volatile("s_waitcnt vmcnt(6)" ::: "memory")
#define GATE8  asm volatile("s_waitcnt vmcnt(8)" ::: "memory")
#define PHI    __builtin_amdgcn_s_setprio(1)
#define PLO    __builtin_amdgcn_s_setprio(0)

// stage one 128-row x 64-col bf16 half-tile (16KB, 512 thr) via
// global_load_lds w=16, inverse-XOR-swizzled global src, linear LDS dest
#define STG(srcrow, ldsbase, half, tile) do {                                   \
    _Pragma("unroll")                                                           \
    for (int it_ = 0; it_ < 2; ++it_) {                                         \
      int p_ = w * 128 + it_ * 64 + lane;                                       \
      int r_ = (half) * 128 + (p_ >> 3);                                        \
      int q8_ = ((p_ & 7) ^ ((p_ >> 3) & 7)) * 8;                               \
      __builtin_amdgcn_global_load_lds(                                         \
          (gas_p)((srcrow) + (size_t)r_ * 2048 + (tile) * 64 + q8_),            \
          (las_p)((char*)(ldsbase) + ((half) * 1024 + w * 128 + it_ * 64) * 16),\
          16, 0, 0);                                                            \
    } } while (0)

// ---------- QKV GEMM: 256x256, pipelined-subtile 8-phase, 1 barrier/phase --
// Unit mapping verified: A reads (mhalf mi) touch rows mi*128+wr*64+0..63 and
// B reads (nhalf ni) rows ni*128+wc*32+0..31 -- each read phase lies entirely
// within ONE 128-row staging unit for every wave.  Region table: every stage
// is >=1 barrier after its region's last read-issue; every first-read is
// >=1 barrier after a GATE8 covering that unit's loads.
#define RDA2(dst, bufi, mi) do {                                                \
    const unsigned short* Ab_ = &As[bufi][0] + (mi)*8192 + wr*4096 + l15*64;    \
    _Pragma("unroll")                                                           \
    for (int f_ = 0; f_ < 4; ++f_) {                                            \
      dst[f_][0] = *(const bf16x8*)(Ab_ + f_*1024 + slot0);                     \
      dst[f_][1] = *(const bf16x8*)(Ab_ + f_*1024 + slot1);                     \
    } } while (0)

#define RDB2(dst, bufi, ni) do {                                                \
    const unsigned short* Bb_ = &Bs[bufi][0] + (ni)*8192 + wc*2048 + l15*64;    \
    _Pragma("unroll")                                                           \
    for (int g_ = 0; g_ < 2; ++g_) {                                            \
      dst[g_][0] = *(const bf16x8*)(Bb_ + g_*1024 + slot0);                     \
      dst[g_][1] = *(const bf16x8*)(Bb_ + g_*1024 + slot1);                     \
    } } while (0)

#define MMQ(ra, rb, mi, ni) do {                                                \
    _Pragma("unroll")                                                           \
    for (int f_ = 0; f_ < 4; ++f_)                                              \
      _Pragma("unroll")                                                         \
      for (int g_ = 0; g_ < 2; ++g_) {                                          \
        acc[(mi)*4+f_][(ni)*2+g_] = __builtin_amdgcn_mfma_f32_16x16x32_bf16(    \
            ra[f_][0], rb[g_][0], acc[(mi)*4+f_][(ni)*2+g_], 0, 0, 0);          \
        acc[(mi)*4+f_][(ni)*2+g_] = __builtin_amdgcn_mfma_f32_16x16x32_bf16(    \
            ra[f_][1], rb[g_][1], acc[(mi)*4+f_][(ni)*2+g_], 0, 0, 0);          \
      } } while (0)

__global__ __launch_bounds__(512)
void gemm8(const unsigned short* __restrict__ A,
           const unsigned short* __restrict__ BT,
           unsigned short* __restrict__ qkvb,
           unsigned short* __restrict__ vTb,
           const float* __restrict__ freqs) {
    __shared__ unsigned short As[2][16384];        // 2 x 32KB
    __shared__ unsigned short Bs[2][16384];        // 2 x 32KB

    int tid  = threadIdx.x;
    int lane = tid & 63, w = tid >> 6;
    int l15  = lane & 15, quad = lane >> 4;
    int wr = w >> 2, wc = w & 3;                   // 2M x 4N waves
    int bid = blockIdx.y * 12 + blockIdx.x;        // T1 swizzle (192 % 8 == 0)
    int s_  = (bid & 7) * 24 + (bid >> 3);
    int by  = s_ / 12, bx = s_ % 12;
    int row0 = by * 256, col0 = bx * 256;
    int slot0 = (quad ^ (lane & 7)) * 8;
    int slot1 = slot0 ^ 32;

    const unsigned short* Arow = A  + (size_t)row0 * 2048;
    const unsigned short* Brow = BT + (size_t)col0 * 2048;

    f32x4 acc[8][4];
    #pragma unroll
    for (int i = 0; i < 8; ++i)
        #pragma unroll
        for (int j = 0; j < 4; ++j) acc[i][j] = f32x4{0.f, 0.f, 0.f, 0.f};

    bf16x8 ra0[4][2], ra1[4][2];    // A frag sets (m-half 0 / 1)
    bf16x8 rb0[2][2], rb1[2][2];    // B frag sets (n-half 0 / 1)

    // prologue: tiles 0 and 1 fully staged (8 units); GATE8 -> tile0 landed
    STG(Brow, &Bs[0][0], 0, 0);
    STG(Arow, &As[0][0], 0, 0);
    STG(Arow, &As[0][0], 1, 0);
    STG(Brow, &Bs[0][0], 1, 0);
    STG(Brow, &Bs[1][0], 0, 1);
    STG(Arow, &As[1][0], 0, 1);
    STG(Arow, &As[1][0], 1, 1);
    STG(Brow, &Bs[1][0], 1, 1);
    GATE8;
    BAR;
    RDB2(rb0, 0, 0);               // "prev-ph6" read
    RDA2(ra0, 0, 0);               // "prev-ph7" read

    #pragma unroll 1
    for (int i = 0; i < 16; ++i) {
        int t  = 2 * i;
        int t2 = (t + 2 > 31) ? 31 : t + 2;        // clamped: dead-region fill
        int t3 = (t + 3 > 31) ? 31 : t + 3;
        // ph0: MFMA Q00(t)
        RDA2(ra1, 0, 1);
        PHI; MMQ(ra0, rb0, 0, 0); PLO;
        STG(Brow, &Bs[0][0], 0, t2);
        BAR;
        // ph1: Q10(t)
        RDB2(rb1, 0, 1);
        PHI; MMQ(ra1, rb0, 1, 0); PLO;
        STG(Arow, &As[0][0], 0, t2);
        GATE8; BAR;
        // ph2: Q01(t)
        RDB2(rb0, 1, 0);
        PHI; MMQ(ra0, rb1, 0, 1); PLO;
        STG(Arow, &As[0][0], 1, t2);
        BAR;
        // ph3: Q11(t)
        RDA2(ra0, 1, 0);
        PHI; MMQ(ra1, rb1, 1, 1); PLO;
        STG(Brow, &Bs[0][0], 1, t2);
        GATE8; BAR;
        // ph4: Q00(t+1)
        RDA2(ra1, 1, 1);
        PHI; MMQ(ra0, rb0, 0, 0); PLO;
        STG(Brow, &Bs[1][0], 0, t3);
        BAR;
        // ph5: Q10(t+1)
        RDB2(rb1, 1, 1);
        PHI; MMQ(ra1, rb0, 1, 0); PLO;
        STG(Arow, &As[1][0], 0, t3);
        GATE8; BAR;
        // ph6: Q01(t+1)
        RDB2(rb0, 0, 0);
        PHI; MMQ(ra0, rb1, 0, 1); PLO;
        STG(Arow, &As[1][0], 1, t3);
        BAR;
        // ph7: Q11(t+1)
        RDA2(ra0, 0, 0);
        PHI; MMQ(ra1, rb1, 1, 1); PLO;
        STG(Brow, &Bs[1][0], 1, t3);
        GATE8; BAR;
    }

    // ---------------- epilogue ----------------
    // C/D 16x16 layout: col = lane&15, row = quad*4 + reg  [m89/m91]
    int q4 = quad * 4;
    if (col0 < 2560) {                    // Q or K cols: fused RoPE
        #pragma unroll
        for (int mi = 0; mi < 2; ++mi)
        #pragma unroll
        for (int f = 0; f < 4; ++f) {
            int mb = row0 + mi*128 + wr*64 + f*16 + q4;
            #pragma unroll
            for (int ni = 0; ni < 2; ++ni)
            #pragma unroll
            for (int g = 0; g < 2; ++g) {
                int colb = col0 + ni*128 + wc*32 + g*16 + l15;
                int dd = (colb & 127) & ~1;
                bool odd = colb & 1;
                #pragma unroll
                for (int rr = 0; rr < 4; ++rr) {
                    int m = mb + rr;
                    int s = m & 2047;
                    float v  = acc[mi*4 + f][ni*2 + g][rr];
                    float pv = __shfl_xor(v, 1);
                    float cs = freqs[s*128 + dd];
                    float sn = freqs[s*128 + dd + 1];
                    float o  = odd ? (pv*sn + v*cs) : (v*cs - pv*sn);
                    qkvb[(size_t)m * NQKV + colb] = f2b(o);
                }
            }
        }
    } else {                              // V cols: transposed store
        #pragma unroll
        for (int mi = 0; mi < 2; ++mi)
        #pragma unroll
        for (int f = 0; f < 4; ++f) {
            int mb = row0 + mi*128 + wr*64 + f*16 + q4;
            int s0 = mb & 2047;
            #pragma unroll
            for (int ni = 0; ni < 2; ++ni)
            #pragma unroll
            for (int g = 0; g < 2; ++g) {
                int colb = col0 + ni*128 + wc*32 + g*16 + l15;
                int vrow = (row0 >> 11) * 512 + (colb - 2560);
                ushort4 ov;
                ov.x = f2b(acc[mi*4 + f][ni*2 + g][0]);
                ov.y = f2b(acc[mi*4 + f][ni*2 + g][1]);
                ov.z = f2b(acc[mi*4 + f][ni*2 + g][2]);
                ov.w = f2b(acc[mi*4 + f][ni*2 + g][3]);
                *(ushort4*)(vTb + (size_t)vrow * 2048 + s0) = ov;
            }
        }
    }
}

// ---------- OUT GEMM: 128x128 tile, 256 thr, pipelined, CORRECTED gates ----
// BUG FIX (r4): reads select units by wr/wc (64-row blocks), NOT by pp --
// a pp0 read touches u1 for wr=1/wc=1 waves.  So BOTH units of a buffer's
// A (or B) must be staged+gated before that buffer's first A (B) read phase.
// Slots: ph0:A1u1<-t+1  ph1:A0u0<-t+2  ph2:A0u1  ph3:B0u0  ph4:B0u1
//        ph5:A1u0<-t+3  ph6:B1u0  ph7:B1u1
// Gates: GATE2@ph1, GATE4@ph3, GATE2@ph5, GATE4@ph7.
//   first-read A0(t+2)@ph7: staged ph1/ph2, covered by ph5-GATE2.
//   first-read B0(t+2)@ph6: staged ph3/ph4, covered by ph5-GATE2.
//   first-read B1(t+3)@next-ph2: staged ph6/ph7, covered by next-ph1-GATE2.
//   first-read A1(t+3)@next-ph3: staged ph5/next-ph0, covered next-ph1-GATE2.
// Overwrites: each slot >=1 barrier after its region's last read-issue.
#define STGO(srcrow, ldsbase, unit, tile) do {                                  \
    _Pragma("unroll")                                                           \
    for (int it_ = 0; it_ < 2; ++it_) {                                         \
      int p_ = w * 128 + it_ * 64 + lane;                                       \
      int r_ = (unit) * 64 + (p_ >> 3);                                         \
      int q8_ = ((p_ & 7) ^ ((p_ >> 3) & 7)) * 8;                               \
      __builtin_amdgcn_global_load_lds(                                         \
          (gas_p)((srcrow) + (size_t)r_ * 2048 + (tile) * 64 + q8_),            \
          (las_p)((char*)(ldsbase) + ((unit) * 512 + w * 128 + it_ * 64) * 16), \
          16, 0, 0);                                                            \
    } } while (0)

#define RDA3(dst, bufi, pp) do {                                                \
    const unsigned short* Ab_ = &As[bufi][0] + wr*4096 + l15*64;                \
    _Pragma("unroll")                                                           \
    for (int f_ = 0; f_ < 2; ++f_) {                                            \
      dst[f_][0] = *(const bf16x8*)(Ab_ + ((pp)*2+f_)*1024 + slot0);            \
      dst[f_][1] = *(const bf16x8*)(Ab_ + ((pp)*2+f_)*1024 + slot1);            \
    } } while (0)

#define RDB3(dst, bufi, pp) do {                                                \
    const unsigned short* Bb_ = &Bs[bufi][0] + wc*4096 + l15*64;                \
    _Pragma("unroll")                                                           \
    for (int g_ = 0; g_ < 2; ++g_) {                                            \
      dst[g_][0] = *(const bf16x8*)(Bb_ + ((pp)*2+g_)*1024 + slot0);            \
      dst[g_][1] = *(const bf16x8*)(Bb_ + ((pp)*2+g_)*1024 + slot1);            \
    } } while (0)

#define MMQ3(ra, rb, mi, ni) do {                                               \
    _Pragma("unroll")                                                           \
    for (int f_ = 0; f_ < 2; ++f_)                                              \
      _Pragma("unroll")                                                         \
      for (int g_ = 0; g_ < 2; ++g_) {                                          \
        acc[(mi)*2+f_][(ni)*2+g_] = __builtin_amdgcn_mfma_f32_16x16x32_bf16(    \
            ra[f_][0], rb[g_][0], acc[(mi)*2+f_][(ni)*2+g_], 0, 0, 0);          \
        acc[(mi)*2+f_][(ni)*2+g_] = __builtin_amdgcn_mfma_f32_16x16x32_bf16(    \
            ra[f_][1], rb[g_][1], acc[(mi)*2+f_][(ni)*2+g_], 0, 0, 0);          \
      } } while (0)

__global__ __launch_bounds__(256)
void gemm8o(const unsigned short* __restrict__ A,
            const unsigned short* __restrict__ BT,
            float* __restrict__ Cf) {
    __shared__ unsigned short As[2][8192];         // 2 x 16KB (128 x 64)
    __shared__ unsigned short Bs[2][8192];         // 2 x 16KB (128 x 64)

    int tid  = threadIdx.x;
    int lane = tid & 63, w = tid >> 6;             // w in 0..3
    int l15  = lane & 15, quad = lane >> 4;
    int wr = w >> 1, wc = w & 1;                   // 2M x 2N waves
    int bid = blockIdx.y * 16 + blockIdx.x;        // T1 swizzle (512 % 8 == 0)
    int s_  = (bid & 7) * 64 + (bid >> 3);
    int by  = s_ >> 4, bx = s_ & 15;
    int row0 = by * 128, col0 = bx * 128;
    int slot0 = (quad ^ (lane & 7)) * 8;
    int slot1 = slot0 ^ 32;

    const unsigned short* Arow = A  + (size_t)row0 * 2048;
    const unsigned short* Brow = BT + (size_t)col0 * 2048;

    f32x4 acc[4][4];
    #pragma unroll
    for (int i = 0; i < 4; ++i)
        #pragma unroll
        for (int j = 0; j < 4; ++j) acc[i][j] = f32x4{0.f, 0.f, 0.f, 0.f};

    bf16x8 a0[2][2], a1[2][2], b0[2][2], b1[2][2];

    // prologue: tile0 all 4 units + tile1's A1u0,B1u0,B1u1 (A1u1 at iter0-ph0)
    STGO(Arow, &As[0][0], 0, 0);
    STGO(Arow, &As[0][0], 1, 0);
    STGO(Brow, &Bs[0][0], 0, 0);
    STGO(Brow, &Bs[0][0], 1, 0);
    STGO(Arow, &As[1][0], 0, 1);
    STGO(Brow, &Bs[1][0], 0, 1);
    STGO(Brow, &Bs[1][0], 1, 1);
    GATE6;                    // tile0's 8 loads landed; tile1's 6 in flight
    BAR;
    RDB3(b0, 0, 0);
    RDA3(a0, 0, 0);

    #pragma unroll 1
    for (int i = 0; i < 16; ++i) {
        int t  = 2 * i;
        int t2 = (t + 2 > 31) ? 31 : t + 2;
        int t3 = (t + 3 > 31) ? 31 : t + 3;
        // ph0: Q00(t)
        RDA3(a1, 0, 1);
        PHI; MMQ3(a0, b0, 0, 0); PLO;
        STGO(Arow, &As[1][0], 1, t + 1);
        BAR;
        // ph1: Q10(t)
        RDB3(b1, 0, 1);
        PHI; MMQ3(a1, b0, 1, 0); PLO;
        STGO(Arow, &As[0][0], 0, t2);
        GATE2; BAR;
        // ph2: Q01(t)
        RDB3(b0, 1, 0);
        PHI; MMQ3(a0, b1, 0, 1); PLO;
        STGO(Arow, &As[0][0], 1, t2);
        BAR;
        // ph3: Q11(t)
        RDA3(a0, 1, 0);
        PHI; MMQ3(a1, b1, 1, 1); PLO;
        STGO(Brow, &Bs[0][0], 0, t2);
        GATE4; BAR;
        // ph4: Q00(t+1)
        RDA3(a1, 1, 1);
        PHI; MMQ3(a0, b0, 0, 0); PLO;
        STGO(Brow, &Bs[0][0], 1, t2);
        BAR;
        // ph5: Q10(t+1)
        RDB3(b1, 1, 1);
        PHI; MMQ3(a1, b0, 1, 0); PLO;
        STGO(Arow, &As[1][0], 0, t3);
        GATE2; BAR;
        // ph6: Q01(t+1)
        RDB3(b0, 0, 0);
        PHI; MMQ3(a0, b1, 0, 1); PLO;
        STGO(Brow, &Bs[1][0], 0, t3);
        BAR;
        // ph7: Q11(t+1)
        RDA3(a0, 0, 0);
        PHI; MMQ3(a1, b1, 1, 1); PLO;
        STGO(Brow, &Bs[1][0], 1, t3);
        GATE4; BAR;
    }

    // epilogue: f32 C, layout col=l15, row=quad*4+rr
    int q4 = quad * 4;
    #pragma unroll
    for (int f = 0; f < 4; ++f) {
        int mb = row0 + wr*64 + f*16 + q4;
        #pragma unroll
        for (int g = 0; g < 4; ++g) {
            int colb = col0 + wc*64 + g*16 + l15;
            #pragma unroll
            for (int rr = 0; rr < 4; ++rr)
                Cf[(size_t)(mb + rr) * 2048 + colb] = acc[f][g][rr];
        }
    }
}

// ---------- GQA-fused MFMA flash attention (unchanged) ---------------------
__global__ __launch_bounds__(512)
void attn_mfma(const unsigned short* __restrict__ qkv,
               const unsigned short* __restrict__ vT,
               unsigned short* __restrict__ ao,
               unsigned short* __restrict__ wsP,
               float2* __restrict__ wsML) {
    __shared__ unsigned short Ks[64 * 128];   // 16KB, XOR-swizzled
    __shared__ unsigned short Vt[128 * 64];   // 16KB, XOR-swizzled

    int tid  = threadIdx.x;
    int lane = tid & 63, w = tid >> 6;        // w in 0..7
    int quad = lane >> 4, l15 = lane & 15;
    int hw = w >> 1, qhalf = w & 1;
    int bx = blockIdx.x, hk = blockIdx.y, b = blockIdx.z;
    int h = hk * 4 + hw;

    int qt, c;
    if (bx < 12)      { qt = 31 - bx / 3;        c = bx % 3; }
    else if (bx < 40) { qt = 27 - (bx - 12) / 2; c = (bx - 12) & 1; }
    else              { qt = 53 - bx;            c = 0; }
    int nt = qt + 1;
    int nch = (qt >= 28) ? 3 : (qt >= 14 ? 2 : 1);
    int kt_begin = c * 14;
    int kt_end = (nt < (c + 1) * 14) ? nt : (c + 1) * 14;
    bool lastc = (c == nch - 1);
    int q0 = qt * 64;
    const float scale = 0.08838834764831845f;   // 1/sqrt(128)

    bf16x8 aq[2][4];
    #pragma unroll
    for (int qf = 0; qf < 2; qf++) {
        const unsigned short* qrow =
            qkv + (size_t)(b*2048 + q0 + qhalf*32 + qf*16 + l15) * NQKV + h*128;
        #pragma unroll
        for (int k4 = 0; k4 < 4; k4++)
            aq[qf][k4] = *(const bf16x8*)(qrow + k4*32 + quad*8);
    }

    int koff[4][4];
    #pragma unroll
    for (int j = 0; j < 4; j++) {
        int row = ((j >> 1) * 32) + ((l15 >> 2) * 8) + ((j & 1) * 4) + (l15 & 3);
        #pragma unroll
        for (int k4 = 0; k4 < 4; k4++) {
            int slot = (k4 * 4 + quad) ^ (row & 15);
            koff[j][k4] = (row * 16 + slot) * 8;
        }
    }
    int vbase0 = (l15 * 8 + (quad ^ (l15 & 7))) * 8;
    int vbase1 = (l15 * 8 + ((4 + quad) ^ (l15 & 7))) * 8;

    const unsigned short* kb0 = qkv + (size_t)(b*2048) * NQKV + 2048 + hk*128;
    const unsigned short* vb0 = vT + (size_t)(b*512 + hk*128) * 2048;

    auto stage_k = [&](int kt) {
        #pragma unroll
        for (int it = 0; it < 2; it++) {
            int s = w * 128 + it * 64 + lane;
            int r = s >> 4, qp = s & 15;
            int q = qp ^ (r & 15);
            __builtin_amdgcn_global_load_lds(
                (gas_p)(kb0 + (size_t)(kt*64 + r) * NQKV + q * 8),
                (las_p)((char*)&Ks[0] + (w * 128 + it * 64) * 16),
                16, 0, 0);
        }
    };
    auto stage_v = [&](int kt) {
        #pragma unroll
        for (int it = 0; it < 2; it++) {
            int s = w * 128 + it * 64 + lane;
            int r = s >> 3, qp = s & 7;
            int q = qp ^ (r & 7);
            __builtin_amdgcn_global_load_lds(
                (gas_p)(vb0 + (size_t)r * 2048 + kt*64 + q * 8),
                (las_p)((char*)&Vt[0] + (w * 128 + it * 64) * 16),
                16, 0, 0);
        }
    };

    f32x4 o_acc[2][8];
    const f32x4 zf = {0.f, 0.f, 0.f, 0.f};
    #pragma unroll
    for (int qf = 0; qf < 2; qf++)
        #pragma unroll
        for (int jn = 0; jn < 8; jn++) o_acc[qf][jn] = zf;
    float m_i[2] = {-1e30f, -1e30f}, l_i[2] = {0.f, 0.f};
    int qglob[2] = {q0 + qhalf*32 + l15, q0 + qhalf*32 + 16 + l15};

    stage_k(kt_begin);
    for (int kt = kt_begin; kt < kt_end; kt++) {
        __syncthreads();             // A: K(kt) landed; V buffer free
        stage_v(kt);                 // async during QK+softmax

        f32x4 s_acc[2][4];
        #pragma unroll
        for (int j = 0; j < 4; j++) {
            s_acc[0][j] = zf; s_acc[1][j] = zf;
            #pragma unroll
            for (int k4 = 0; k4 < 4; k4++) {
                bf16x8 ak = *(const bf16x8*)&Ks[koff[j][k4]];
                s_acc[0][j] = __builtin_amdgcn_mfma_f32_16x16x32_bf16(ak, aq[0][k4], s_acc[0][j], 0, 0, 0);
                s_acc[1][j] = __builtin_amdgcn_mfma_f32_16x16x32_bf16(ak, aq[1][k4], s_acc[1][j], 0, 0, 0);
            }
        }

        bf16x8 pp[2][2];
        #pragma unroll
        for (int qf = 0; qf < 2; qf++) {
            float sv[4][4];
            #pragma unroll
            for (int j = 0; j < 4; j++)
                #pragma unroll
                for (int r = 0; r < 4; r++)
                    sv[j][r] = s_acc[qf][j][r] * scale;
            if (kt == qt) {
                #pragma unroll
                for (int j = 0; j < 4; j++)
                    #pragma unroll
                    for (int r = 0; r < 4; r++) {
                        int sloc = ((j >> 1) * 32) + quad*8 + ((j & 1) * 4) + r;
                        if (kt*64 + sloc > qglob[qf]) sv[j][r] = -1e30f;
                    }
            }
            float mx = sv[0][0];
            #pragma unroll
            for (int j = 0; j < 4; j++)
                #pragma unroll
                for (int r = 0; r < 4; r++) mx = fmaxf(mx, sv[j][r]);
            mx = fmaxf(mx, __shfl_xor(mx, 16));
            mx = fmaxf(mx, __shfl_xor(mx, 32));
            float mnew = fmaxf(m_i[qf], mx);
            float alpha = __expf(m_i[qf] - mnew);
            float rs = 0.f;
            float p[4][4];
            #pragma unroll
            for (int j = 0; j < 4; j++)
                #pragma unroll
                for (int r = 0; r < 4; r++) {
                    p[j][r] = __expf(sv[j][r] - mnew);
                    rs += p[j][r];
                }
            l_i[qf] = l_i[qf] * alpha + rs;
            m_i[qf] = mnew;
            #pragma unroll
            for (int jn = 0; jn < 8; jn++)
                #pragma unroll
                for (int r = 0; r < 4; r++) o_acc[qf][jn][r] *= alpha;
            #pragma unroll
            for (int r = 0; r < 4; r++) {
                pp[qf][0][r]     = (short)f2b(p[0][r]);
                pp[qf][0][r + 4] = (short)f2b(p[1][r]);
                pp[qf][1][r]     = (short)f2b(p[2][r]);
                pp[qf][1][r + 4] = (short)f2b(p[3][r]);
            }
        }

        __syncthreads();             // B: V(kt) landed; K buffer free
        if (kt + 1 < kt_end) stage_k(kt + 1);

        #pragma unroll
        for (int jn = 0; jn < 8; jn++) {
            bf16x8 av0 = *(const bf16x8*)&Vt[jn*1024 + vbase0];
            bf16x8 av1 = *(const bf16x8*)&Vt[jn*1024 + vbase1];
            o_acc[0][jn] = __builtin_amdgcn_mfma_f32_16x16x32_bf16(av0, pp[0][0], o_acc[0][jn], 0, 0, 0);
            o_acc[0][jn] = __builtin_amdgcn_mfma_f32_16x16x32_bf16(av1, pp[0][1], o_acc[0][jn], 0, 0, 0);
            o_acc[1][jn] = __builtin_amdgcn_mfma_f32_16x16x32_bf16(av0, pp[1][0], o_acc[1][jn], 0, 0, 0);
            o_acc[1][jn] = __builtin_amdgcn_mfma_f32_16x16x32_bf16(av1, pp[1][1], o_acc[1][jn], 0, 0, 0);
        }
    }

    int pi = 0, mi = 0;
    if (qt >= 14) {
        if (qt < 28) { mi = (qt - 14) * 2 + c;       pi = qt - 14; }
        else         { mi = 28 + (qt - 28) * 3 + c;  pi = 14 + (qt - 28) * 2 + c; }
    }
    #pragma unroll
    for (int qf = 0; qf < 2; qf++) {
        float lt = l_i[qf];
        lt += __shfl_xor(lt, 16);
        lt += __shfl_xor(lt, 32);
        float inv = 1.f / lt;
        int q_local = qhalf * 32 + qf * 16 + l15;
        unsigned short* dst;
        if (lastc)
            dst = ao + (size_t)(b*2048 + q0 + q_local) * 2048 + h*128;
        else
            dst = wsP + (size_t)(((pi * 8 + hk * 2 + b) * 4 + hw) * 64 + q_local) * 128;
        #pragma unroll
        for (int jn = 0; jn < 8; jn++) {
            ushort4 ov;
            ov.x = f2b(o_acc[qf][jn][0] * inv);
            ov.y = f2b(o_acc[qf][jn][1] * inv);
            ov.z = f2b(o_acc[qf][jn][2] * inv);
            ov.w = f2b(o_acc[qf][jn][3] * inv);
            *(ushort4*)(dst + jn*16 + quad*4) = ov;
        }
        if (qt >= 14 && quad == 0)
            wsML[(mi * 8 + hk * 2 + b) * 256 + hw * 64 + q_local]
                = make_float2(m_i[qf], lt);
    }
}

// ---------- merge split-K partials (rows q >= 896, 2-3 chunks) -------------
__global__ __launch_bounds__(256)
void merge_kernel(unsigned short* __restrict__ ao,
                  const unsigned short* __restrict__ wsP,
                  const float2* __restrict__ wsML) {
    int t = blockIdx.x * 256 + threadIdx.x;
    int d = (t & 15) * 8;
    int h = (t >> 4) & 15;
    int rest = t >> 8;                // 0..2303
    int q_off = rest % 1152;
    int b = rest / 1152;
    int q = 896 + q_off;
    int qt = q >> 6, q_local = q & 63;
    int hk = h >> 2, hw = h & 3;
    int nch = (qt >= 28) ? 3 : 2;

    float mv[3], lv[3];
    for (int cc = 0; cc < nch; cc++) {
        int mi = (qt < 28) ? (qt - 14) * 2 + cc : 28 + (qt - 28) * 3 + cc;
        float2 ml = wsML[(mi * 8 + hk * 2 + b) * 256 + hw * 64 + q_local];
        mv[cc] = ml.x; lv[cc] = ml.y;
    }
    float M = mv[0];
    for (int cc = 1; cc < nch; cc++) M = fmaxf(M, mv[cc]);
    float f[3], S = 0.f;
    for (int cc = 0; cc < nch; cc++) { f[cc] = __expf(mv[cc] - M) * lv[cc]; S += f[cc]; }
    float inv = 1.f / S;

    unsigned short* arow = ao + (size_t)(b*2048 + q) * 2048 + h*128 + d;
    float outv[8];
    {
        ushort4 a0 = *(ushort4*)arow, a1 = *(ushort4*)(arow + 4);
        float fl = f[nch-1];
        outv[0] = fl*b2f(a0.x); outv[1] = fl*b2f(a0.y);
        outv[2] = fl*b2f(a0.z); outv[3] = fl*b2f(a0.w);
        outv[4] = fl*b2f(a1.x); outv[5] = fl*b2f(a1.y);
        outv[6] = fl*b2f(a1.z); outv[7] = fl*b2f(a1.w);
    }
    for (int cc = 0; cc < nch - 1; cc++) {
        int pi = (qt < 28) ? (qt - 14) : 14 + (qt - 28) * 2 + cc;
        const unsigned short* prow =
            wsP + (size_t)(((pi * 8 + hk * 2 + b) * 4 + hw) * 64 + q_local) * 128 + d;
        ushort4 p0 = *(const ushort4*)prow, p1 = *(const ushort4*)(prow + 4);
        float fc = f[cc];
        outv[0] += fc*b2f(p0.x); outv[1] += fc*b2f(p0.y);
        outv[2] += fc*b2f(p0.z); outv[3] += fc*b2f(p0.w);
        outv[4] += fc*b2f(p1.x); outv[5] += fc*b2f(p1.y);
        outv[6] += fc*b2f(p1.z); outv[7] += fc*b2f(p1.w);
    }
    ushort4 o0, o1;
    o0.x = f2b(outv[0]*inv); o0.y = f2b(outv[1]*inv);
    o0.z = f2b(outv[2]*inv); o0.w = f2b(outv[3]*inv);
    o1.x = f2b(outv[4]*inv); o1.y = f2b(outv[5]*inv);
    o1.z = f2b(outv[6]*inv); o1.w = f2b(outv[7]*inv);
    *(ushort4*)arow = o0;
    *(ushort4*)(arow + 4) = o1;
}

// ---------- launch ---------------------------------------------------------
extern "C" void kernel_launch(void* const* d_in, const int* in_sizes, int n_in,
                              void* d_out, int out_size, void* d_ws, size_t ws_size,
                              hipStream_t stream) {
    const float* x     = (const float*)d_in[0];
    const float* freqs = (const float*)d_in[1];
    const float* wq    = (const float*)d_in[2];
    const float* wk    = (const float*)d_in[3];
    const float* wv    = (const float*)d_in[4];
    const float* wo    = (const float*)d_in[5];
    float* out = (float*)d_out;

    char* ws = (char*)d_ws;
    unsigned short* xbf    = (unsigned short*)(ws);                  // 16MB
    unsigned short* aobuf  = (unsigned short*)(ws);                  // alias (xbf dead)
    unsigned short* wqkvT  = (unsigned short*)(ws + (16u<<20));      // 12MB
    unsigned short* woT    = (unsigned short*)(ws + (28u<<20));      // 8MB
    unsigned short* qkvbuf = (unsigned short*)(ws + (36u<<20));      // 24MB
    unsigned short* vTbuf  = (unsigned short*)(ws + (60u<<20));      // 4MB
    unsigned short* wsP  = (unsigned short*)(ws + (16u<<20));        // 11MB (aliases wqkvT, dead)
    float2*         wsML = (float2*)(ws + (16u<<20) + 176u*65536u);  // 640KB

    dim3 blk(256);
    convert_x<<<8192, blk, 0, stream>>>(x, xbf);
    convert_w_all<<<dim3(64, 64, 4), blk, 0, stream>>>(wq, wk, wv, wo, wqkvT, woT);
    gemm8<<<dim3(NQKV/256, M_/256), dim3(512), 0, stream>>>(
        xbf, wqkvT, qkvbuf, vTbuf, freqs);
    attn_mfma<<<dim3(54, 4, 2), dim3(512), 0, stream>>>(qkvbuf, vTbuf, aobuf, wsP, wsML);
    merge_kernel<<<2304, blk, 0, stream>>>(aobuf, wsP, wsML);
    gemm8o<<<dim3(2048/128, M_/128), blk, 0, stream>>>(aobuf, woT, out);
}

// Round 6
// 319.315 us; speedup vs baseline: 1.0292x; 1.0292x over previous
//
#include <hip/hip_runtime.h>
#include <hip/hip_bf16.h>

#define B_   2
#define S_   2048
#define HID_ 2048
#define H_   16
#define KVH_ 4
#define D_   128
#define M_   4096
#define NQKV 3072

typedef __attribute__((ext_vector_type(8))) short bf16x8;    // 8 bf16 = 4 VGPR
typedef __attribute__((ext_vector_type(4))) float f32x4;
typedef const __attribute__((address_space(1))) unsigned int* gas_p;
typedef __attribute__((address_space(3))) unsigned int* las_p;

__device__ __forceinline__ unsigned short f2b(float f) {
    __hip_bfloat16 h = __float2bfloat16(f);
    return *reinterpret_cast<unsigned short*>(&h);
}
__device__ __forceinline__ float b2f(unsigned short u) {
    __hip_bfloat16 h;
    *reinterpret_cast<unsigned short*>(&h) = u;
    return __bfloat162float(h);
}

// ---------- convert x: fp32 -> bf16 ----------------------------------------
__global__ __launch_bounds__(256)
void convert_x(const float* __restrict__ x, unsigned short* __restrict__ xb) {
    int i = (blockIdx.x * 256 + threadIdx.x) * 4;
    float4 v = *(const float4*)(x + i);
    ushort4 o;
    o.x = f2b(v.x); o.y = f2b(v.y); o.z = f2b(v.z); o.w = f2b(v.w);
    *(ushort4*)(xb + i) = o;
}

// ---------- all four weight converts in one launch (z selects matrix) ------
__global__ __launch_bounds__(256)
void convert_w_all(const float* __restrict__ wq, const float* __restrict__ wk,
                   const float* __restrict__ wv, const float* __restrict__ wo,
                   unsigned short* __restrict__ wqkvT,
                   unsigned short* __restrict__ woT) {
    __shared__ float tile[32][33];
    int z = blockIdx.z;
    const float* w; int N, nbase; unsigned short* dst;
    if (z == 0)      { w = wq; N = 2048; nbase = 0;    dst = wqkvT; }
    else if (z == 1) { w = wk; N = 512;  nbase = 2048; dst = wqkvT; }
    else if (z == 2) { w = wv; N = 512;  nbase = 2560; dst = wqkvT; }
    else             { w = wo; N = 2048; nbase = 0;    dst = woT; }
    int n0 = blockIdx.x * 32, k0 = blockIdx.y * 32;
    if (n0 >= N) return;
    int tx = threadIdx.x & 31, ty = threadIdx.x >> 5;
    #pragma unroll
    for (int j = 0; j < 4; j++)
        tile[ty + j*8][tx] = w[(size_t)(k0 + ty + j*8) * N + n0 + tx];
    __syncthreads();
    #pragma unroll
    for (int j = 0; j < 4; j++)
        dst[(size_t)(nbase + n0 + ty + j*8) * 2048 + k0 + tx] = f2b(tile[tx][ty + j*8]);
}

// ---------- shared 8-phase machinery ---------------------------------------
#define BAR    asm volatile("s_barrier" ::: "memory")
#define LG0    do { asm volatile("s_waitcnt lgkmcnt(0)" ::: "memory"); \
                    __builtin_amdgcn_sched_barrier(0); } while (0)
#define GATE0  asm volatile("s_waitcnt vmcnt(0)" ::: "memory")
#define GATE6  asm volatile("s_waitcnt vmcnt(6)" ::: "memory")
#define GATE8  asm volatile("s_waitcnt vmcnt(8)" ::: "memory")
#define PHI    __builtin_amdgcn_s_setprio(1)
#define PLO    __builtin_amdgcn_s_setprio(0)

// stage one 128-row x 64-col bf16 half-tile (16KB, 512 thr) via
// global_load_lds w=16, inverse-XOR-swizzled global src, linear LDS dest
#define STG(srcrow, ldsbase, half, tile) do {                                   \
    _Pragma("unroll")                                                           \
    for (int it_ = 0; it_ < 2; ++it_) {                                         \
      int p_ = w * 128 + it_ * 64 + lane;                                       \
      int r_ = (half) * 128 + (p_ >> 3);                                        \
      int q8_ = ((p_ & 7) ^ ((p_ >> 3) & 7)) * 8;                               \
      __builtin_amdgcn_global_load_lds(                                         \
          (gas_p)((srcrow) + (size_t)r_ * 2048 + (tile) * 64 + q8_),            \
          (las_p)((char*)(ldsbase) + ((half) * 1024 + w * 128 + it_ * 64) * 16),\
          16, 0, 0);                                                            \
    } } while (0)

// ---------- QKV GEMM: 256x256, pipelined-subtile 8-phase (r5, verified) ----
// r6 tweak: STG issued BEFORE the MFMA cluster (loads enter the VMEM queue
// ~155cy earlier per phase; same region/gate discipline -- audited per-phase:
// no in-phase read touches the region its own STG overwrites).
// r6 tweak 2: Q columns (colb < 2048) pre-scaled by 1/sqrt(D) in the RoPE
// epilogue, so attn drops its per-tile scale multiply.
#define RDA2(dst, bufi, mi) do {                                                \
    const unsigned short* Ab_ = &As[bufi][0] + (mi)*8192 + wr*4096 + l15*64;    \
    _Pragma("unroll")                                                           \
    for (int f_ = 0; f_ < 4; ++f_) {                                            \
      dst[f_][0] = *(const bf16x8*)(Ab_ + f_*1024 + slot0);                     \
      dst[f_][1] = *(const bf16x8*)(Ab_ + f_*1024 + slot1);                     \
    } } while (0)

#define RDB2(dst, bufi, ni) do {                                                \
    const unsigned short* Bb_ = &Bs[bufi][0] + (ni)*8192 + wc*2048 + l15*64;    \
    _Pragma("unroll")                                                           \
    for (int g_ = 0; g_ < 2; ++g_) {                                            \
      dst[g_][0] = *(const bf16x8*)(Bb_ + g_*1024 + slot0);                     \
      dst[g_][1] = *(const bf16x8*)(Bb_ + g_*1024 + slot1);                     \
    } } while (0)

#define MMQ(ra, rb, mi, ni) do {                                                \
    _Pragma("unroll")                                                           \
    for (int f_ = 0; f_ < 4; ++f_)                                              \
      _Pragma("unroll")                                                         \
      for (int g_ = 0; g_ < 2; ++g_) {                                          \
        acc[(mi)*4+f_][(ni)*2+g_] = __builtin_amdgcn_mfma_f32_16x16x32_bf16(    \
            ra[f_][0], rb[g_][0], acc[(mi)*4+f_][(ni)*2+g_], 0, 0, 0);          \
        acc[(mi)*4+f_][(ni)*2+g_] = __builtin_amdgcn_mfma_f32_16x16x32_bf16(    \
            ra[f_][1], rb[g_][1], acc[(mi)*4+f_][(ni)*2+g_], 0, 0, 0);          \
      } } while (0)

__global__ __launch_bounds__(512)
void gemm8(const unsigned short* __restrict__ A,
           const unsigned short* __restrict__ BT,
           unsigned short* __restrict__ qkvb,
           unsigned short* __restrict__ vTb,
           const float* __restrict__ freqs) {
    __shared__ unsigned short As[2][16384];        // 2 x 32KB
    __shared__ unsigned short Bs[2][16384];        // 2 x 32KB

    int tid  = threadIdx.x;
    int lane = tid & 63, w = tid >> 6;
    int l15  = lane & 15, quad = lane >> 4;
    int wr = w >> 2, wc = w & 3;                   // 2M x 4N waves
    int bid = blockIdx.y * 12 + blockIdx.x;        // T1 swizzle (192 % 8 == 0)
    int s_  = (bid & 7) * 24 + (bid >> 3);
    int by  = s_ / 12, bx = s_ % 12;
    int row0 = by * 256, col0 = bx * 256;
    int slot0 = (quad ^ (lane & 7)) * 8;
    int slot1 = slot0 ^ 32;

    const unsigned short* Arow = A  + (size_t)row0 * 2048;
    const unsigned short* Brow = BT + (size_t)col0 * 2048;

    f32x4 acc[8][4];
    #pragma unroll
    for (int i = 0; i < 8; ++i)
        #pragma unroll
        for (int j = 0; j < 4; ++j) acc[i][j] = f32x4{0.f, 0.f, 0.f, 0.f};

    bf16x8 ra0[4][2], ra1[4][2];    // A frag sets (m-half 0 / 1)
    bf16x8 rb0[2][2], rb1[2][2];    // B frag sets (n-half 0 / 1)

    // prologue: tiles 0 and 1 fully staged (8 units); GATE8 -> tile0 landed
    STG(Brow, &Bs[0][0], 0, 0);
    STG(Arow, &As[0][0], 0, 0);
    STG(Arow, &As[0][0], 1, 0);
    STG(Brow, &Bs[0][0], 1, 0);
    STG(Brow, &Bs[1][0], 0, 1);
    STG(Arow, &As[1][0], 0, 1);
    STG(Arow, &As[1][0], 1, 1);
    STG(Brow, &Bs[1][0], 1, 1);
    GATE8;
    BAR;
    RDB2(rb0, 0, 0);               // "prev-ph6" read
    RDA2(ra0, 0, 0);               // "prev-ph7" read

    #pragma unroll 1
    for (int i = 0; i < 16; ++i) {
        int t  = 2 * i;
        int t2 = (t + 2 > 31) ? 31 : t + 2;        // clamped: dead-region fill
        int t3 = (t + 3 > 31) ? 31 : t + 3;
        // ph0: MFMA Q00(t)
        RDA2(ra1, 0, 1);
        STG(Brow, &Bs[0][0], 0, t2);
        PHI; MMQ(ra0, rb0, 0, 0); PLO;
        BAR;
        // ph1: Q10(t)
        RDB2(rb1, 0, 1);
        STG(Arow, &As[0][0], 0, t2);
        PHI; MMQ(ra1, rb0, 1, 0); PLO;
        GATE8; BAR;
        // ph2: Q01(t)
        RDB2(rb0, 1, 0);
        STG(Arow, &As[0][0], 1, t2);
        PHI; MMQ(ra0, rb1, 0, 1); PLO;
        BAR;
        // ph3: Q11(t)
        RDA2(ra0, 1, 0);
        STG(Brow, &Bs[0][0], 1, t2);
        PHI; MMQ(ra1, rb1, 1, 1); PLO;
        GATE8; BAR;
        // ph4: Q00(t+1)
        RDA2(ra1, 1, 1);
        STG(Brow, &Bs[1][0], 0, t3);
        PHI; MMQ(ra0, rb0, 0, 0); PLO;
        BAR;
        // ph5: Q10(t+1)
        RDB2(rb1, 1, 1);
        STG(Arow, &As[1][0], 0, t3);
        PHI; MMQ(ra1, rb0, 1, 0); PLO;
        GATE8; BAR;
        // ph6: Q01(t+1)
        RDB2(rb0, 0, 0);
        STG(Arow, &As[1][0], 1, t3);
        PHI; MMQ(ra0, rb1, 0, 1); PLO;
        BAR;
        // ph7: Q11(t+1)
        RDA2(ra0, 0, 0);
        STG(Brow, &Bs[1][0], 1, t3);
        PHI; MMQ(ra1, rb1, 1, 1); PLO;
        GATE8; BAR;
    }

    // ---------------- epilogue ----------------
    // C/D 16x16 layout: col = lane&15, row = quad*4 + reg  [m89/m91]
    int q4 = quad * 4;
    if (col0 < 2560) {                    // Q or K cols: fused RoPE
        const float qscale = 0.08838834764831845f;   // 1/sqrt(128), Q only
        #pragma unroll
        for (int mi = 0; mi < 2; ++mi)
        #pragma unroll
        for (int f = 0; f < 4; ++f) {
            int mb = row0 + mi*128 + wr*64 + f*16 + q4;
            #pragma unroll
            for (int ni = 0; ni < 2; ++ni)
            #pragma unroll
            for (int g = 0; g < 2; ++g) {
                int colb = col0 + ni*128 + wc*32 + g*16 + l15;
                int dd = (colb & 127) & ~1;
                bool odd = colb & 1;
                float sc = (colb < 2048) ? qscale : 1.f;
                #pragma unroll
                for (int rr = 0; rr < 4; ++rr) {
                    int m = mb + rr;
                    int s = m & 2047;
                    float v  = acc[mi*4 + f][ni*2 + g][rr];
                    float pv = __shfl_xor(v, 1);
                    float cs = freqs[s*128 + dd];
                    float sn = freqs[s*128 + dd + 1];
                    float o  = odd ? (pv*sn + v*cs) : (v*cs - pv*sn);
                    qkvb[(size_t)m * NQKV + colb] = f2b(o * sc);
                }
            }
        }
    } else {                              // V cols: transposed store
        #pragma unroll
        for (int mi = 0; mi < 2; ++mi)
        #pragma unroll
        for (int f = 0; f < 4; ++f) {
            int mb = row0 + mi*128 + wr*64 + f*16 + q4;
            int s0 = mb & 2047;
            #pragma unroll
            for (int ni = 0; ni < 2; ++ni)
            #pragma unroll
            for (int g = 0; g < 2; ++g) {
                int colb = col0 + ni*128 + wc*32 + g*16 + l15;
                int vrow = (row0 >> 11) * 512 + (colb - 2560);
                ushort4 ov;
                ov.x = f2b(acc[mi*4 + f][ni*2 + g][0]);
                ov.y = f2b(acc[mi*4 + f][ni*2 + g][1]);
                ov.z = f2b(acc[mi*4 + f][ni*2 + g][2]);
                ov.w = f2b(acc[mi*4 + f][ni*2 + g][3]);
                *(ushort4*)(vTb + (size_t)vrow * 2048 + s0) = ov;
            }
        }
    }
}

// ---------- OUT GEMM: 256x128-tile 8-phase template (r1 version, verified) -
// Reverted from r5's 128^2 pipelined variant (r5 was ~13.6us slower).
// 8 waves as 4M x 2N -> per-wave 64x64.  LDS 96KB: A[2][256x64], B[2][128x64].
// GATE6 at ph3/ph7; region safety as verified in r2 (passed harness).
#define RDAo(bufi) do {                                                         \
    const unsigned short* Ab_ = &As[bufi][0] + wr * 4096 + l15 * 64;            \
    _Pragma("unroll")                                                           \
    for (int f_ = 0; f_ < 4; ++f_) {                                            \
      af[f_][0] = *(const bf16x8*)(Ab_ + f_ * 1024 + slot0);                    \
      af[f_][1] = *(const bf16x8*)(Ab_ + f_ * 1024 + slot1);                    \
    } } while (0)

#define RDBo(bufi, g) do {                                                      \
    const unsigned short* Bb_ = &Bs[bufi][0] + wc * 4096 + l15 * 64;            \
    bfr[g][0] = *(const bf16x8*)(Bb_ + (g) * 1024 + slot0);                     \
    bfr[g][1] = *(const bf16x8*)(Bb_ + (g) * 1024 + slot1);                     \
    } while (0)

#define MM8o(mi, ni) do {                                                       \
    _Pragma("unroll")                                                           \
    for (int f_ = 2*(mi); f_ < 2*(mi)+2; ++f_)                                  \
      _Pragma("unroll")                                                         \
      for (int g_ = 2*(ni); g_ < 2*(ni)+2; ++g_) {                              \
        acc[f_][g_] = __builtin_amdgcn_mfma_f32_16x16x32_bf16(                  \
            af[f_][0], bfr[g_][0], acc[f_][g_], 0, 0, 0);                       \
        acc[f_][g_] = __builtin_amdgcn_mfma_f32_16x16x32_bf16(                  \
            af[f_][1], bfr[g_][1], acc[f_][g_], 0, 0, 0);                       \
      } } while (0)

__global__ __launch_bounds__(512)
void gemm8o(const unsigned short* __restrict__ A,
            const unsigned short* __restrict__ BT,
            float* __restrict__ Cf) {
    __shared__ unsigned short As[2][16384];        // 2 x 32KB (256 x 64)
    __shared__ unsigned short Bs[2][8192];         // 2 x 16KB (128 x 64)

    int tid  = threadIdx.x;
    int lane = tid & 63, w = tid >> 6;
    int l15  = lane & 15, quad = lane >> 4;
    int wr = w >> 1, wc = w & 1;                   // 4M x 2N wave grid
    int bid = blockIdx.y * 16 + blockIdx.x;        // T1 (nwg=256, 256%8==0)
    int s_  = (bid & 7) * 32 + (bid >> 3);
    int by  = s_ >> 4, bx = s_ & 15;
    int row0 = by * 256, col0 = bx * 128;
    int slot0 = (quad ^ (lane & 7)) * 8;
    int slot1 = slot0 ^ 32;

    const unsigned short* Arow = A  + (size_t)row0 * 2048;
    const unsigned short* Brow = BT + (size_t)col0 * 2048;

    f32x4 acc[4][4];
    #pragma unroll
    for (int i = 0; i < 4; ++i)
        #pragma unroll
        for (int j = 0; j < 4; ++j) acc[i][j] = f32x4{0.f, 0.f, 0.f, 0.f};

    bf16x8 af[4][2];          // wave's 4 A frags x 2 k-chunks
    bf16x8 bfr[4][2];         // wave's 4 B frags x 2 k-chunks

    // prologue: full tiles 0 (buf0) and 1 (buf1), 6 units = 12 loads
    STG(Arow, &As[0][0], 0, 0);
    STG(Arow, &As[0][0], 1, 0);
    STG(Brow, &Bs[0][0], 0, 0);
    STG(Arow, &As[1][0], 0, 1);
    STG(Arow, &As[1][0], 1, 1);
    STG(Brow, &Bs[1][0], 0, 1);
    GATE6;                    // tile0 landed; tile1's 6 in flight
    BAR;

    #pragma unroll 1
    for (int i = 0; i < 15; ++i) {
        int t = 2 * i;
        // ph0: all A frags + B g0,g1
        RDAo(0); RDBo(0, 0); RDBo(0, 1);
        BAR; LG0; PHI; MM8o(0, 0); PLO; BAR;
        // ph1: B g2,g3; stage A0(t+2)
        RDBo(0, 2); RDBo(0, 3); STG(Arow, &As[0][0], 0, t + 2);
        BAR; LG0; PHI; MM8o(0, 1); PLO; BAR;
        // ph2: stage A1(t+2)
        STG(Arow, &As[0][0], 1, t + 2);
        BAR; LG0; PHI; MM8o(1, 0); PLO; BAR;
        // ph3: stage B(t+2); gate tile t+1
        STG(Brow, &Bs[0][0], 0, t + 2);
        BAR; LG0; PHI; MM8o(1, 1); PLO; GATE6; BAR;
        // ph4 (buf1)
        RDAo(1); RDBo(1, 0); RDBo(1, 1);
        BAR; LG0; PHI; MM8o(0, 0); PLO; BAR;
        // ph5
        RDBo(1, 2); RDBo(1, 3); STG(Arow, &As[1][0], 0, t + 3);
        BAR; LG0; PHI; MM8o(0, 1); PLO; BAR;
        // ph6
        STG(Arow, &As[1][0], 1, t + 3);
        BAR; LG0; PHI; MM8o(1, 0); PLO; BAR;
        // ph7
        STG(Brow, &Bs[1][0], 0, t + 3);
        BAR; LG0; PHI; MM8o(1, 1); PLO; GATE6; BAR;
    }
    // tail: t = 30, 31 (no staging; tile31 gated at ph3)
    RDAo(0); RDBo(0, 0); RDBo(0, 1);
    BAR; LG0; PHI; MM8o(0, 0); PLO; BAR;
    RDBo(0, 2); RDBo(0, 3);
    BAR; LG0; PHI; MM8o(0, 1); PLO; BAR;
    BAR; LG0; PHI; MM8o(1, 0); PLO; BAR;
    BAR; LG0; PHI; MM8o(1, 1); PLO; GATE0; BAR;
    RDAo(1); RDBo(1, 0); RDBo(1, 1);
    BAR; LG0; PHI; MM8o(0, 0); PLO; BAR;
    RDBo(1, 2); RDBo(1, 3);
    BAR; LG0; PHI; MM8o(0, 1); PLO; BAR;
    BAR; LG0; PHI; MM8o(1, 0); PLO; BAR;
    LG0; PHI; MM8o(1, 1); PLO;

    // epilogue: f32 C, layout col=l15, row=quad*4+rr
    int q4 = quad * 4;
    #pragma unroll
    for (int f = 0; f < 4; ++f) {
        int mb = row0 + wr*64 + f*16 + q4;
        #pragma unroll
        for (int g = 0; g < 4; ++g) {
            int colb = col0 + wc*64 + g*16 + l15;
            #pragma unroll
            for (int rr = 0; rr < 4; ++rr)
                Cf[(size_t)(mb + rr) * 2048 + colb] = acc[f][g][rr];
        }
    }
}

// ---------- GQA-fused MFMA flash attention ---------------------------------
// r6: Q arrives pre-scaled by 1/sqrt(D) (gemm8 epilogue) -> no per-tile scale
// mul.  T13 defer-max (THR=8): skip O-rescale + m-update when the tile max
// didn't grow past m_i+8 (P bounded by e^8; f32 accum safe; merge unaffected).
__global__ __launch_bounds__(512)
void attn_mfma(const unsigned short* __restrict__ qkv,
               const unsigned short* __restrict__ vT,
               unsigned short* __restrict__ ao,
               unsigned short* __restrict__ wsP,
               float2* __restrict__ wsML) {
    __shared__ unsigned short Ks[64 * 128];   // 16KB, XOR-swizzled
    __shared__ unsigned short Vt[128 * 64];   // 16KB, XOR-swizzled

    int tid  = threadIdx.x;
    int lane = tid & 63, w = tid >> 6;        // w in 0..7
    int quad = lane >> 4, l15 = lane & 15;
    int hw = w >> 1, qhalf = w & 1;
    int bx = blockIdx.x, hk = blockIdx.y, b = blockIdx.z;
    int h = hk * 4 + hw;

    int qt, c;
    if (bx < 12)      { qt = 31 - bx / 3;        c = bx % 3; }
    else if (bx < 40) { qt = 27 - (bx - 12) / 2; c = (bx - 12) & 1; }
    else              { qt = 53 - bx;            c = 0; }
    int nt = qt + 1;
    int nch = (qt >= 28) ? 3 : (qt >= 14 ? 2 : 1);
    int kt_begin = c * 14;
    int kt_end = (nt < (c + 1) * 14) ? nt : (c + 1) * 14;
    bool lastc = (c == nch - 1);
    int q0 = qt * 64;

    bf16x8 aq[2][4];
    #pragma unroll
    for (int qf = 0; qf < 2; qf++) {
        const unsigned short* qrow =
            qkv + (size_t)(b*2048 + q0 + qhalf*32 + qf*16 + l15) * NQKV + h*128;
        #pragma unroll
        for (int k4 = 0; k4 < 4; k4++)
            aq[qf][k4] = *(const bf16x8*)(qrow + k4*32 + quad*8);
    }

    int koff[4][4];
    #pragma unroll
    for (int j = 0; j < 4; j++) {
        int row = ((j >> 1) * 32) + ((l15 >> 2) * 8) + ((j & 1) * 4) + (l15 & 3);
        #pragma unroll
        for (int k4 = 0; k4 < 4; k4++) {
            int slot = (k4 * 4 + quad) ^ (row & 15);
            koff[j][k4] = (row * 16 + slot) * 8;
        }
    }
    int vbase0 = (l15 * 8 + (quad ^ (l15 & 7))) * 8;
    int vbase1 = (l15 * 8 + ((4 + quad) ^ (l15 & 7))) * 8;

    const unsigned short* kb0 = qkv + (size_t)(b*2048) * NQKV + 2048 + hk*128;
    const unsigned short* vb0 = vT + (size_t)(b*512 + hk*128) * 2048;

    auto stage_k = [&](int kt) {
        #pragma unroll
        for (int it = 0; it < 2; it++) {
            int s = w * 128 + it * 64 + lane;
            int r = s >> 4, qp = s & 15;
            int q = qp ^ (r & 15);
            __builtin_amdgcn_global_load_lds(
                (gas_p)(kb0 + (size_t)(kt*64 + r) * NQKV + q * 8),
                (las_p)((char*)&Ks[0] + (w * 128 + it * 64) * 16),
                16, 0, 0);
        }
    };
    auto stage_v = [&](int kt) {
        #pragma unroll
        for (int it = 0; it < 2; it++) {
            int s = w * 128 + it * 64 + lane;
            int r = s >> 3, qp = s & 7;
            int q = qp ^ (r & 7);
            __builtin_amdgcn_global_load_lds(
                (gas_p)(vb0 + (size_t)r * 2048 + kt*64 + q * 8),
                (las_p)((char*)&Vt[0] + (w * 128 + it * 64) * 16),
                16, 0, 0);
        }
    };

    f32x4 o_acc[2][8];
    const f32x4 zf = {0.f, 0.f, 0.f, 0.f};
    #pragma unroll
    for (int qf = 0; qf < 2; qf++)
        #pragma unroll
        for (int jn = 0; jn < 8; jn++) o_acc[qf][jn] = zf;
    float m_i[2] = {-1e30f, -1e30f}, l_i[2] = {0.f, 0.f};
    int qglob[2] = {q0 + qhalf*32 + l15, q0 + qhalf*32 + 16 + l15};

    stage_k(kt_begin);
    for (int kt = kt_begin; kt < kt_end; kt++) {
        __syncthreads();             // A: K(kt) landed; V buffer free
        stage_v(kt);                 // async during QK+softmax

        f32x4 s_acc[2][4];
        #pragma unroll
        for (int j = 0; j < 4; j++) {
            s_acc[0][j] = zf; s_acc[1][j] = zf;
            #pragma unroll
            for (int k4 = 0; k4 < 4; k4++) {
                bf16x8 ak = *(const bf16x8*)&Ks[koff[j][k4]];
                s_acc[0][j] = __builtin_amdgcn_mfma_f32_16x16x32_bf16(ak, aq[0][k4], s_acc[0][j], 0, 0, 0);
                s_acc[1][j] = __builtin_amdgcn_mfma_f32_16x16x32_bf16(ak, aq[1][k4], s_acc[1][j], 0, 0, 0);
            }
        }

        bf16x8 pp[2][2];
        #pragma unroll
        for (int qf = 0; qf < 2; qf++) {
            float sv[4][4];
            #pragma unroll
            for (int j = 0; j < 4; j++)
                #pragma unroll
                for (int r = 0; r < 4; r++)
                    sv[j][r] = s_acc[qf][j][r];          // Q pre-scaled
            if (kt == qt) {
                #pragma unroll
                for (int j = 0; j < 4; j++)
                    #pragma unroll
                    for (int r = 0; r < 4; r++) {
                        int sloc = ((j >> 1) * 32) + quad*8 + ((j & 1) * 4) + r;
                        if (kt*64 + sloc > qglob[qf]) sv[j][r] = -1e30f;
                    }
            }
            float mx = sv[0][0];
            #pragma unroll
            for (int j = 0; j < 4; j++)
                #pragma unroll
                for (int r = 0; r < 4; r++) mx = fmaxf(mx, sv[j][r]);
            mx = fmaxf(mx, __shfl_xor(mx, 16));
            mx = fmaxf(mx, __shfl_xor(mx, 32));
            // T13 defer-max: keep old m when tile max grew <= 8
            int defer = __all(mx <= m_i[qf] + 8.f);
            float mnew = defer ? m_i[qf] : fmaxf(m_i[qf], mx);
            float rs = 0.f;
            float p[4][4];
            #pragma unroll
            for (int j = 0; j < 4; j++)
                #pragma unroll
                for (int r = 0; r < 4; r++) {
                    p[j][r] = __expf(sv[j][r] - mnew);
                    rs += p[j][r];
                }
            if (!defer) {
                float alpha = __expf(m_i[qf] - mnew);
                l_i[qf] *= alpha;
                #pragma unroll
                for (int jn = 0; jn < 8; jn++)
                    #pragma unroll
                    for (int r = 0; r < 4; r++) o_acc[qf][jn][r] *= alpha;
                m_i[qf] = mnew;
            }
            l_i[qf] += rs;
            #pragma unroll
            for (int r = 0; r < 4; r++) {
                pp[qf][0][r]     = (short)f2b(p[0][r]);
                pp[qf][0][r + 4] = (short)f2b(p[1][r]);
                pp[qf][1][r]     = (short)f2b(p[2][r]);
                pp[qf][1][r + 4] = (short)f2b(p[3][r]);
            }
        }

        __syncthreads();             // B: V(kt) landed; K buffer free
        if (kt + 1 < kt_end) stage_k(kt + 1);

        #pragma unroll
        for (int jn = 0; jn < 8; jn++) {
            bf16x8 av0 = *(const bf16x8*)&Vt[jn*1024 + vbase0];
            bf16x8 av1 = *(const bf16x8*)&Vt[jn*1024 + vbase1];
            o_acc[0][jn] = __builtin_amdgcn_mfma_f32_16x16x32_bf16(av0, pp[0][0], o_acc[0][jn], 0, 0, 0);
            o_acc[0][jn] = __builtin_amdgcn_mfma_f32_16x16x32_bf16(av1, pp[0][1], o_acc[0][jn], 0, 0, 0);
            o_acc[1][jn] = __builtin_amdgcn_mfma_f32_16x16x32_bf16(av0, pp[1][0], o_acc[1][jn], 0, 0, 0);
            o_acc[1][jn] = __builtin_amdgcn_mfma_f32_16x16x32_bf16(av1, pp[1][1], o_acc[1][jn], 0, 0, 0);
        }
    }

    int pi = 0, mi = 0;
    if (qt >= 14) {
        if (qt < 28) { mi = (qt - 14) * 2 + c;       pi = qt - 14; }
        else         { mi = 28 + (qt - 28) * 3 + c;  pi = 14 + (qt - 28) * 2 + c; }
    }
    #pragma unroll
    for (int qf = 0; qf < 2; qf++) {
        float lt = l_i[qf];
        lt += __shfl_xor(lt, 16);
        lt += __shfl_xor(lt, 32);
        float inv = 1.f / lt;
        int q_local = qhalf * 32 + qf * 16 + l15;
        unsigned short* dst;
        if (lastc)
            dst = ao + (size_t)(b*2048 + q0 + q_local) * 2048 + h*128;
        else
            dst = wsP + (size_t)(((pi * 8 + hk * 2 + b) * 4 + hw) * 64 + q_local) * 128;
        #pragma unroll
        for (int jn = 0; jn < 8; jn++) {
            ushort4 ov;
            ov.x = f2b(o_acc[qf][jn][0] * inv);
            ov.y = f2b(o_acc[qf][jn][1] * inv);
            ov.z = f2b(o_acc[qf][jn][2] * inv);
            ov.w = f2b(o_acc[qf][jn][3] * inv);
            *(ushort4*)(dst + jn*16 + quad*4) = ov;
        }
        if (qt >= 14 && quad == 0)
            wsML[(mi * 8 + hk * 2 + b) * 256 + hw * 64 + q_local]
                = make_float2(m_i[qf], lt);
    }
}

// ---------- merge split-K partials (rows q >= 896, 2-3 chunks) -------------
__global__ __launch_bounds__(256)
void merge_kernel(unsigned short* __restrict__ ao,
                  const unsigned short* __restrict__ wsP,
                  const float2* __restrict__ wsML) {
    int t = blockIdx.x * 256 + threadIdx.x;
    int d = (t & 15) * 8;
    int h = (t >> 4) & 15;
    int rest = t >> 8;                // 0..2303
    int q_off = rest % 1152;
    int b = rest / 1152;
    int q = 896 + q_off;
    int qt = q >> 6, q_local = q & 63;
    int hk = h >> 2, hw = h & 3;
    int nch = (qt >= 28) ? 3 : 2;

    float mv[3], lv[3];
    for (int cc = 0; cc < nch; cc++) {
        int mi = (qt < 28) ? (qt - 14) * 2 + cc : 28 + (qt - 28) * 3 + cc;
        float2 ml = wsML[(mi * 8 + hk * 2 + b) * 256 + hw * 64 + q_local];
        mv[cc] = ml.x; lv[cc] = ml.y;
    }
    float M = mv[0];
    for (int cc = 1; cc < nch; cc++) M = fmaxf(M, mv[cc]);
    float f[3], S = 0.f;
    for (int cc = 0; cc < nch; cc++) { f[cc] = __expf(mv[cc] - M) * lv[cc]; S += f[cc]; }
    float inv = 1.f / S;

    unsigned short* arow = ao + (size_t)(b*2048 + q) * 2048 + h*128 + d;
    float outv[8];
    {
        ushort4 a0 = *(ushort4*)arow, a1 = *(ushort4*)(arow + 4);
        float fl = f[nch-1];
        outv[0] = fl*b2f(a0.x); outv[1] = fl*b2f(a0.y);
        outv[2] = fl*b2f(a0.z); outv[3] = fl*b2f(a0.w);
        outv[4] = fl*b2f(a1.x); outv[5] = fl*b2f(a1.y);
        outv[6] = fl*b2f(a1.z); outv[7] = fl*b2f(a1.w);
    }
    for (int cc = 0; cc < nch - 1; cc++) {
        int pi = (qt < 28) ? (qt - 14) : 14 + (qt - 28) * 2 + cc;
        const unsigned short* prow =
            wsP + (size_t)(((pi * 8 + hk * 2 + b) * 4 + hw) * 64 + q_local) * 128 + d;
        ushort4 p0 = *(const ushort4*)prow, p1 = *(const ushort4*)(prow + 4);
        float fc = f[cc];
        outv[0] += fc*b2f(p0.x); outv[1] += fc*b2f(p0.y);
        outv[2] += fc*b2f(p0.z); outv[3] += fc*b2f(p0.w);
        outv[4] += fc*b2f(p1.x); outv[5] += fc*b2f(p1.y);
        outv[6] += fc*b2f(p1.z); outv[7] += fc*b2f(p1.w);
    }
    ushort4 o0, o1;
    o0.x = f2b(outv[0]*inv); o0.y = f2b(outv[1]*inv);
    o0.z = f2b(outv[2]*inv); o0.w = f2b(outv[3]*inv);
    o1.x = f2b(outv[4]*inv); o1.y = f2b(outv[5]*inv);
    o1.z = f2b(outv[6]*inv); o1.w = f2b(outv[7]*inv);
    *(ushort4*)arow = o0;
    *(ushort4*)(arow + 4) = o1;
}

// ---------- launch ---------------------------------------------------------
extern "C" void kernel_launch(void* const* d_in, const int* in_sizes, int n_in,
                              void* d_out, int out_size, void* d_ws, size_t ws_size,
                              hipStream_t stream) {
    const float* x     = (const float*)d_in[0];
    const float* freqs = (const float*)d_in[1];
    const float* wq    = (const float*)d_in[2];
    const float* wk    = (const float*)d_in[3];
    const float* wv    = (const float*)d_in[4];
    const float* wo    = (const float*)d_in[5];
    float* out = (float*)d_out;

    char* ws = (char*)d_ws;
    unsigned short* xbf    = (unsigned short*)(ws);                  // 16MB
    unsigned short* aobuf  = (unsigned short*)(ws);                  // alias (xbf dead)
    unsigned short* wqkvT  = (unsigned short*)(ws + (16u<<20));      // 12MB
    unsigned short* woT    = (unsigned short*)(ws + (28u<<20));      // 8MB
    unsigned short* qkvbuf = (unsigned short*)(ws + (36u<<20));      // 24MB
    unsigned short* vTbuf  = (unsigned short*)(ws + (60u<<20));      // 4MB
    unsigned short* wsP  = (unsigned short*)(ws + (16u<<20));        // 11MB (aliases wqkvT, dead)
    float2*         wsML = (float2*)(ws + (16u<<20) + 176u*65536u);  // 640KB

    dim3 blk(256);
    convert_x<<<8192, blk, 0, stream>>>(x, xbf);
    convert_w_all<<<dim3(64, 64, 4), blk, 0, stream>>>(wq, wk, wv, wo, wqkvT, woT);
    gemm8<<<dim3(NQKV/256, M_/256), dim3(512), 0, stream>>>(
        xbf, wqkvT, qkvbuf, vTbuf, freqs);
    attn_mfma<<<dim3(54, 4, 2), dim3(512), 0, stream>>>(qkvbuf, vTbuf, aobuf, wsP, wsML);
    merge_kernel<<<2304, blk, 0, stream>>>(aobuf, wsP, wsML);
    gemm8o<<<dim3(2048/128, M_/256), dim3(512), 0, stream>>>(aobuf, woT, out);
}

// Round 7
// 293.380 us; speedup vs baseline: 1.1202x; 1.0884x over previous
//
#include <hip/hip_runtime.h>
#include <hip/hip_bf16.h>

#define B_   2
#define S_   2048
#define HID_ 2048
#define H_   16
#define KVH_ 4
#define D_   128
#define M_   4096
#define NQKV 3072

typedef __attribute__((ext_vector_type(8))) short bf16x8;    // 8 bf16 = 4 VGPR
typedef __attribute__((ext_vector_type(4))) float f32x4;
typedef const __attribute__((address_space(1))) unsigned int* gas_p;
typedef __attribute__((address_space(3))) unsigned int* las_p;

__device__ __forceinline__ unsigned short f2b(float f) {
    __hip_bfloat16 h = __float2bfloat16(f);
    return *reinterpret_cast<unsigned short*>(&h);
}
__device__ __forceinline__ float b2f(unsigned short u) {
    __hip_bfloat16 h;
    *reinterpret_cast<unsigned short*>(&h) = u;
    return __bfloat162float(h);
}

// ---------- fused converts: z<4 = weight transposes, z>=4 = x cast ---------
__global__ __launch_bounds__(256)
void convert_all(const float* __restrict__ x,
                 const float* __restrict__ wq, const float* __restrict__ wk,
                 const float* __restrict__ wv, const float* __restrict__ wo,
                 unsigned short* __restrict__ xb,
                 unsigned short* __restrict__ wqkvT,
                 unsigned short* __restrict__ woT) {
    int z = blockIdx.z;
    if (z >= 4) {                       // x: fp32 -> bf16, 1024 elems/block
        int lin = ((z - 4) * 64 + blockIdx.y) * 64 + blockIdx.x;
        int i = (lin * 256 + threadIdx.x) * 4;
        float4 v = *(const float4*)(x + i);
        ushort4 o;
        o.x = f2b(v.x); o.y = f2b(v.y); o.z = f2b(v.z); o.w = f2b(v.w);
        *(ushort4*)(xb + i) = o;
        return;
    }
    __shared__ float tile[32][33];
    const float* w; int N, nbase; unsigned short* dst;
    if (z == 0)      { w = wq; N = 2048; nbase = 0;    dst = wqkvT; }
    else if (z == 1) { w = wk; N = 512;  nbase = 2048; dst = wqkvT; }
    else if (z == 2) { w = wv; N = 512;  nbase = 2560; dst = wqkvT; }
    else             { w = wo; N = 2048; nbase = 0;    dst = woT; }
    int n0 = blockIdx.x * 32, k0 = blockIdx.y * 32;
    if (n0 >= N) return;
    int tx = threadIdx.x & 31, ty = threadIdx.x >> 5;
    #pragma unroll
    for (int j = 0; j < 4; j++)
        tile[ty + j*8][tx] = w[(size_t)(k0 + ty + j*8) * N + n0 + tx];
    __syncthreads();
    #pragma unroll
    for (int j = 0; j < 4; j++)
        dst[(size_t)(nbase + n0 + ty + j*8) * 2048 + k0 + tx] = f2b(tile[tx][ty + j*8]);
}

// ---------- shared 8-phase machinery ---------------------------------------
#define BAR    asm volatile("s_barrier" ::: "memory")
#define LG0    do { asm volatile("s_waitcnt lgkmcnt(0)" ::: "memory"); \
                    __builtin_amdgcn_sched_barrier(0); } while (0)
#define GATE0  asm volatile("s_waitcnt vmcnt(0)" ::: "memory")
#define GATE6  asm volatile("s_waitcnt vmcnt(6)" ::: "memory")
#define GATE7  asm volatile("s_waitcnt vmcnt(7)" ::: "memory")
#define PHI    __builtin_amdgcn_s_setprio(1)
#define PLO    __builtin_amdgcn_s_setprio(0)

// stage one 128-row x 64-col bf16 half-tile (16KB, 512 thr, 2 loads/thread)
#define STG(srcrow, ldsbase, half, tile) do {                                   \
    _Pragma("unroll")                                                           \
    for (int it_ = 0; it_ < 2; ++it_) {                                         \
      int p_ = w * 128 + it_ * 64 + lane;                                       \
      int r_ = (half) * 128 + (p_ >> 3);                                        \
      int q8_ = ((p_ & 7) ^ ((p_ >> 3) & 7)) * 8;                               \
      __builtin_amdgcn_global_load_lds(                                         \
          (gas_p)((srcrow) + (size_t)r_ * 2048 + (tile) * 64 + q8_),            \
          (las_p)((char*)(ldsbase) + ((half) * 1024 + w * 128 + it_ * 64) * 16),\
          16, 0, 0);                                                            \
    } } while (0)

// stage one 64-row x 64-col unit (8KB, 512 thr, 1 load/thread)
#define STGB(srcrow, ldsbase, unit, tile) do {                                  \
      int p_ = w * 64 + lane;                                                   \
      int r_ = (unit) * 64 + (p_ >> 3);                                         \
      int q8_ = ((p_ & 7) ^ ((p_ >> 3) & 7)) * 8;                               \
      __builtin_amdgcn_global_load_lds(                                         \
          (gas_p)((srcrow) + (size_t)r_ * 2048 + (tile) * 64 + q8_),            \
          (las_p)((char*)(ldsbase) + ((unit) * 512 + p_) * 16),                 \
          16, 0, 0);                                                            \
    } while (0)

// ---------- QKV GEMM: 256x192 tile, grid 16x16 = 256 blocks = 1/CU ---------
// 8 waves as 4M x 2N -> per-wave 64x96 (4 A-frags x 6 B-frags, 48 MFMA/K-tile)
// LDS 112KB: A[2][256x64]=2x32K, B[2][192x64]=2x24K.
// Stage units/tile: A-half0, A-half1 (2 loads ea), B-u0/u1/u2 (1 load ea) = 7.
// GATE7 at ph3/ph7: 14 outstanding -> oldest 7 (next tile's units) landed.
// ALL B units stage together (ph3/ph7) and gate as a group before any read
// of that buffer (r4 lesson: reads select rows by wc, spanning all units).
// Overwrites: A0@ph1/A1@ph2 after ph0's all-A reads (LG0-drained + barrier);
// B@ph3 after ph1's last B read.  Template schedule verified r1/r2.
#define RDAq(dst, bufi) do {                                                    \
    const unsigned short* Ab_ = &As[bufi][0] + wr*4096 + l15*64;                \
    _Pragma("unroll")                                                           \
    for (int f_ = 0; f_ < 4; ++f_) {                                            \
      dst[f_][0] = *(const bf16x8*)(Ab_ + f_*1024 + slot0);                     \
      dst[f_][1] = *(const bf16x8*)(Ab_ + f_*1024 + slot1);                     \
    } } while (0)

#define RDBq(dst, bufi, nh) do {                                                \
    const unsigned short* Bb_ = &Bs[bufi][0] + wc*6144 + (nh)*3072 + l15*64;    \
    _Pragma("unroll")                                                           \
    for (int g_ = 0; g_ < 3; ++g_) {                                            \
      dst[g_][0] = *(const bf16x8*)(Bb_ + g_*1024 + slot0);                     \
      dst[g_][1] = *(const bf16x8*)(Bb_ + g_*1024 + slot1);                     \
    } } while (0)

#define MMq(mh, rb, nh) do {                                                    \
    _Pragma("unroll")                                                           \
    for (int f_ = 2*(mh); f_ < 2*(mh)+2; ++f_)                                  \
      _Pragma("unroll")                                                         \
      for (int g_ = 0; g_ < 3; ++g_) {                                          \
        acc[f_][(nh)*3+g_] = __builtin_amdgcn_mfma_f32_16x16x32_bf16(           \
            ra[f_][0], rb[g_][0], acc[f_][(nh)*3+g_], 0, 0, 0);                 \
        acc[f_][(nh)*3+g_] = __builtin_amdgcn_mfma_f32_16x16x32_bf16(           \
            ra[f_][1], rb[g_][1], acc[f_][(nh)*3+g_], 0, 0, 0);                 \
      } } while (0)

__global__ __launch_bounds__(512)
void gemm8(const unsigned short* __restrict__ A,
           const unsigned short* __restrict__ BT,
           unsigned short* __restrict__ qkvb,
           unsigned short* __restrict__ vTb,
           const float* __restrict__ freqs) {
    __shared__ unsigned short As[2][16384];        // 2 x 32KB (256 x 64)
    __shared__ unsigned short Bs[2][12288];        // 2 x 24KB (192 x 64)

    int tid  = threadIdx.x;
    int lane = tid & 63, w = tid >> 6;
    int l15  = lane & 15, quad = lane >> 4;
    int wr = w >> 1, wc = w & 1;                   // 4M x 2N waves
    int bid = blockIdx.y * 16 + blockIdx.x;        // T1 swizzle (256 % 8 == 0)
    int s_  = (bid & 7) * 32 + (bid >> 3);
    int by  = s_ >> 4, bx = s_ & 15;
    int row0 = by * 256, col0 = bx * 192;
    int slot0 = (quad ^ (lane & 7)) * 8;
    int slot1 = slot0 ^ 32;

    const unsigned short* Arow = A  + (size_t)row0 * 2048;
    const unsigned short* Brow = BT + (size_t)col0 * 2048;

    f32x4 acc[4][6];
    #pragma unroll
    for (int i = 0; i < 4; ++i)
        #pragma unroll
        for (int j = 0; j < 6; ++j) acc[i][j] = f32x4{0.f, 0.f, 0.f, 0.f};

    bf16x8 ra[4][2];          // wave's 4 A frags x 2 k-chunks
    bf16x8 rbl[3][2];         // B n-half 0 frags
    bf16x8 rbh[3][2];         // B n-half 1 frags

    // prologue: tiles 0 and 1 fully staged (7 loads each); GATE7 -> t0 landed
    STG (Arow, &As[0][0], 0, 0);
    STG (Arow, &As[0][0], 1, 0);
    STGB(Brow, &Bs[0][0], 0, 0);
    STGB(Brow, &Bs[0][0], 1, 0);
    STGB(Brow, &Bs[0][0], 2, 0);
    STG (Arow, &As[1][0], 0, 1);
    STG (Arow, &As[1][0], 1, 1);
    STGB(Brow, &Bs[1][0], 0, 1);
    STGB(Brow, &Bs[1][0], 1, 1);
    STGB(Brow, &Bs[1][0], 2, 1);
    GATE7;
    BAR;

    #pragma unroll 1
    for (int i = 0; i < 15; ++i) {
        int t = 2 * i;
        // ph0: all A frags + B n-half0
        RDAq(ra, 0); RDBq(rbl, 0, 0);
        BAR; LG0; PHI; MMq(0, rbl, 0); PLO; BAR;
        // ph1: B n-half1; stage A0(t+2)
        RDBq(rbh, 0, 1); STG(Arow, &As[0][0], 0, t + 2);
        BAR; LG0; PHI; MMq(0, rbh, 1); PLO; BAR;
        // ph2: stage A1(t+2)
        STG(Arow, &As[0][0], 1, t + 2);
        BAR; LG0; PHI; MMq(1, rbl, 0); PLO; BAR;
        // ph3: stage B(t+2) all 3 units; gate tile t+1
        STGB(Brow, &Bs[0][0], 0, t + 2);
        STGB(Brow, &Bs[0][0], 1, t + 2);
        STGB(Brow, &Bs[0][0], 2, t + 2);
        BAR; LG0; PHI; MMq(1, rbh, 1); PLO; GATE7; BAR;
        // ph4 (buf1)
        RDAq(ra, 1); RDBq(rbl, 1, 0);
        BAR; LG0; PHI; MMq(0, rbl, 0); PLO; BAR;
        // ph5
        RDBq(rbh, 1, 1); STG(Arow, &As[1][0], 0, t + 3);
        BAR; LG0; PHI; MMq(0, rbh, 1); PLO; BAR;
        // ph6
        STG(Arow, &As[1][0], 1, t + 3);
        BAR; LG0; PHI; MMq(1, rbl, 0); PLO; BAR;
        // ph7
        STGB(Brow, &Bs[1][0], 0, t + 3);
        STGB(Brow, &Bs[1][0], 1, t + 3);
        STGB(Brow, &Bs[1][0], 2, t + 3);
        BAR; LG0; PHI; MMq(1, rbh, 1); PLO; GATE7; BAR;
    }
    // tail: t = 30 (buf0), t = 31 (buf1); no staging; GATE0 before buf1 reads
    RDAq(ra, 0); RDBq(rbl, 0, 0);
    BAR; LG0; PHI; MMq(0, rbl, 0); PLO; BAR;
    RDBq(rbh, 0, 1);
    BAR; LG0; PHI; MMq(0, rbh, 1); PLO; BAR;
    BAR; LG0; PHI; MMq(1, rbl, 0); PLO; BAR;
    BAR; LG0; PHI; MMq(1, rbh, 1); PLO; GATE0; BAR;
    RDAq(ra, 1); RDBq(rbl, 1, 0);
    BAR; LG0; PHI; MMq(0, rbl, 0); PLO; BAR;
    RDBq(rbh, 1, 1);
    BAR; LG0; PHI; MMq(0, rbh, 1); PLO; BAR;
    BAR; LG0; PHI; MMq(1, rbl, 0); PLO; BAR;
    LG0; PHI; MMq(1, rbh, 1); PLO;

    // ---------------- epilogue ----------------
    // C/D 16x16 layout: col = lane&15, row = quad*4 + reg  [m89/m91]
    // 192-col tile can straddle the V boundary (2560) -> branch per fragment
    // (2048 and 2560 are 16-aligned, so each 16-col frag is uniform).
    int q4 = quad * 4;
    const float qscale = 0.08838834764831845f;     // 1/sqrt(128), Q only
    #pragma unroll
    for (int f = 0; f < 4; ++f) {
        int mb = row0 + wr*64 + f*16 + q4;
        #pragma unroll
        for (int g = 0; g < 6; ++g) {
            int colbase = col0 + wc*96 + g*16;
            int colb = colbase + l15;
            if (colbase < 2560) {              // Q or K: fused RoPE
                int dd = (colb & 127) & ~1;
                bool odd = colb & 1;
                float sc = (colbase < 2048) ? qscale : 1.f;
                #pragma unroll
                for (int rr = 0; rr < 4; ++rr) {
                    int m = mb + rr;
                    int s = m & 2047;
                    float v  = acc[f][g][rr];
                    float pv = __shfl_xor(v, 1);
                    float cs = freqs[s*128 + dd];
                    float sn = freqs[s*128 + dd + 1];
                    float o  = odd ? (pv*sn + v*cs) : (v*cs - pv*sn);
                    qkvb[(size_t)m * NQKV + colb] = f2b(o * sc);
                }
            } else {                           // V: transposed store
                int vrow = (row0 >> 11) * 512 + (colb - 2560);
                int s0 = mb & 2047;
                ushort4 ov;
                ov.x = f2b(acc[f][g][0]);
                ov.y = f2b(acc[f][g][1]);
                ov.z = f2b(acc[f][g][2]);
                ov.w = f2b(acc[f][g][3]);
                *(ushort4*)(vTb + (size_t)vrow * 2048 + s0) = ov;
            }
        }
    }
}

// ---------- OUT GEMM: 256x128-tile 8-phase template (r1/r2 verified) -------
#define RDAo(bufi) do {                                                         \
    const unsigned short* Ab_ = &As[bufi][0] + wr * 4096 + l15 * 64;            \
    _Pragma("unroll")                                                           \
    for (int f_ = 0; f_ < 4; ++f_) {                                            \
      af[f_][0] = *(const bf16x8*)(Ab_ + f_ * 1024 + slot0);                    \
      af[f_][1] = *(const bf16x8*)(Ab_ + f_ * 1024 + slot1);                    \
    } } while (0)

#define RDBo(bufi, g) do {                                                      \
    const unsigned short* Bb_ = &Bs[bufi][0] + wc * 4096 + l15 * 64;            \
    bfr[g][0] = *(const bf16x8*)(Bb_ + (g) * 1024 + slot0);                     \
    bfr[g][1] = *(const bf16x8*)(Bb_ + (g) * 1024 + slot1);                     \
    } while (0)

#define MM8o(mi, ni) do {                                                       \
    _Pragma("unroll")                                                           \
    for (int f_ = 2*(mi); f_ < 2*(mi)+2; ++f_)                                  \
      _Pragma("unroll")                                                         \
      for (int g_ = 2*(ni); g_ < 2*(ni)+2; ++g_) {                              \
        acc[f_][g_] = __builtin_amdgcn_mfma_f32_16x16x32_bf16(                  \
            af[f_][0], bfr[g_][0], acc[f_][g_], 0, 0, 0);                       \
        acc[f_][g_] = __builtin_amdgcn_mfma_f32_16x16x32_bf16(                  \
            af[f_][1], bfr[g_][1], acc[f_][g_], 0, 0, 0);                       \
      } } while (0)

__global__ __launch_bounds__(512)
void gemm8o(const unsigned short* __restrict__ A,
            const unsigned short* __restrict__ BT,
            float* __restrict__ Cf) {
    __shared__ unsigned short As[2][16384];        // 2 x 32KB (256 x 64)
    __shared__ unsigned short Bs[2][8192];         // 2 x 16KB (128 x 64)

    int tid  = threadIdx.x;
    int lane = tid & 63, w = tid >> 6;
    int l15  = lane & 15, quad = lane >> 4;
    int wr = w >> 1, wc = w & 1;                   // 4M x 2N wave grid
    int bid = blockIdx.y * 16 + blockIdx.x;        // T1 (nwg=256, 256%8==0)
    int s_  = (bid & 7) * 32 + (bid >> 3);
    int by  = s_ >> 4, bx = s_ & 15;
    int row0 = by * 256, col0 = bx * 128;
    int slot0 = (quad ^ (lane & 7)) * 8;
    int slot1 = slot0 ^ 32;

    const unsigned short* Arow = A  + (size_t)row0 * 2048;
    const unsigned short* Brow = BT + (size_t)col0 * 2048;

    f32x4 acc[4][4];
    #pragma unroll
    for (int i = 0; i < 4; ++i)
        #pragma unroll
        for (int j = 0; j < 4; ++j) acc[i][j] = f32x4{0.f, 0.f, 0.f, 0.f};

    bf16x8 af[4][2];
    bf16x8 bfr[4][2];

    STG(Arow, &As[0][0], 0, 0);
    STG(Arow, &As[0][0], 1, 0);
    STG(Brow, &Bs[0][0], 0, 0);
    STG(Arow, &As[1][0], 0, 1);
    STG(Arow, &As[1][0], 1, 1);
    STG(Brow, &Bs[1][0], 0, 1);
    GATE6;
    BAR;

    #pragma unroll 1
    for (int i = 0; i < 15; ++i) {
        int t = 2 * i;
        RDAo(0); RDBo(0, 0); RDBo(0, 1);
        BAR; LG0; PHI; MM8o(0, 0); PLO; BAR;
        RDBo(0, 2); RDBo(0, 3); STG(Arow, &As[0][0], 0, t + 2);
        BAR; LG0; PHI; MM8o(0, 1); PLO; BAR;
        STG(Arow, &As[0][0], 1, t + 2);
        BAR; LG0; PHI; MM8o(1, 0); PLO; BAR;
        STG(Brow, &Bs[0][0], 0, t + 2);
        BAR; LG0; PHI; MM8o(1, 1); PLO; GATE6; BAR;
        RDAo(1); RDBo(1, 0); RDBo(1, 1);
        BAR; LG0; PHI; MM8o(0, 0); PLO; BAR;
        RDBo(1, 2); RDBo(1, 3); STG(Arow, &As[1][0], 0, t + 3);
        BAR; LG0; PHI; MM8o(0, 1); PLO; BAR;
        STG(Arow, &As[1][0], 1, t + 3);
        BAR; LG0; PHI; MM8o(1, 0); PLO; BAR;
        STG(Brow, &Bs[1][0], 0, t + 3);
        BAR; LG0; PHI; MM8o(1, 1); PLO; GATE6; BAR;
    }
    RDAo(0); RDBo(0, 0); RDBo(0, 1);
    BAR; LG0; PHI; MM8o(0, 0); PLO; BAR;
    RDBo(0, 2); RDBo(0, 3);
    BAR; LG0; PHI; MM8o(0, 1); PLO; BAR;
    BAR; LG0; PHI; MM8o(1, 0); PLO; BAR;
    BAR; LG0; PHI; MM8o(1, 1); PLO; GATE0; BAR;
    RDAo(1); RDBo(1, 0); RDBo(1, 1);
    BAR; LG0; PHI; MM8o(0, 0); PLO; BAR;
    RDBo(1, 2); RDBo(1, 3);
    BAR; LG0; PHI; MM8o(0, 1); PLO; BAR;
    BAR; LG0; PHI; MM8o(1, 0); PLO; BAR;
    LG0; PHI; MM8o(1, 1); PLO;

    int q4 = quad * 4;
    #pragma unroll
    for (int f = 0; f < 4; ++f) {
        int mb = row0 + wr*64 + f*16 + q4;
        #pragma unroll
        for (int g = 0; g < 4; ++g) {
            int colb = col0 + wc*64 + g*16 + l15;
            #pragma unroll
            for (int rr = 0; rr < 4; ++rr)
                Cf[(size_t)(mb + rr) * 2048 + colb] = acc[f][g][rr];
        }
    }
}

// ---------- GQA-fused MFMA flash attention (r6 version, verified) ----------
__global__ __launch_bounds__(512)
void attn_mfma(const unsigned short* __restrict__ qkv,
               const unsigned short* __restrict__ vT,
               unsigned short* __restrict__ ao,
               unsigned short* __restrict__ wsP,
               float2* __restrict__ wsML) {
    __shared__ unsigned short Ks[64 * 128];   // 16KB, XOR-swizzled
    __shared__ unsigned short Vt[128 * 64];   // 16KB, XOR-swizzled

    int tid  = threadIdx.x;
    int lane = tid & 63, w = tid >> 6;        // w in 0..7
    int quad = lane >> 4, l15 = lane & 15;
    int hw = w >> 1, qhalf = w & 1;
    int bx = blockIdx.x, hk = blockIdx.y, b = blockIdx.z;
    int h = hk * 4 + hw;

    int qt, c;
    if (bx < 12)      { qt = 31 - bx / 3;        c = bx % 3; }
    else if (bx < 40) { qt = 27 - (bx - 12) / 2; c = (bx - 12) & 1; }
    else              { qt = 53 - bx;            c = 0; }
    int nt = qt + 1;
    int nch = (qt >= 28) ? 3 : (qt >= 14 ? 2 : 1);
    int kt_begin = c * 14;
    int kt_end = (nt < (c + 1) * 14) ? nt : (c + 1) * 14;
    bool lastc = (c == nch - 1);
    int q0 = qt * 64;

    bf16x8 aq[2][4];
    #pragma unroll
    for (int qf = 0; qf < 2; qf++) {
        const unsigned short* qrow =
            qkv + (size_t)(b*2048 + q0 + qhalf*32 + qf*16 + l15) * NQKV + h*128;
        #pragma unroll
        for (int k4 = 0; k4 < 4; k4++)
            aq[qf][k4] = *(const bf16x8*)(qrow + k4*32 + quad*8);
    }

    int koff[4][4];
    #pragma unroll
    for (int j = 0; j < 4; j++) {
        int row = ((j >> 1) * 32) + ((l15 >> 2) * 8) + ((j & 1) * 4) + (l15 & 3);
        #pragma unroll
        for (int k4 = 0; k4 < 4; k4++) {
            int slot = (k4 * 4 + quad) ^ (row & 15);
            koff[j][k4] = (row * 16 + slot) * 8;
        }
    }
    int vbase0 = (l15 * 8 + (quad ^ (l15 & 7))) * 8;
    int vbase1 = (l15 * 8 + ((4 + quad) ^ (l15 & 7))) * 8;

    const unsigned short* kb0 = qkv + (size_t)(b*2048) * NQKV + 2048 + hk*128;
    const unsigned short* vb0 = vT + (size_t)(b*512 + hk*128) * 2048;

    auto stage_k = [&](int kt) {
        #pragma unroll
        for (int it = 0; it < 2; it++) {
            int s = w * 128 + it * 64 + lane;
            int r = s >> 4, qp = s & 15;
            int q = qp ^ (r & 15);
            __builtin_amdgcn_global_load_lds(
                (gas_p)(kb0 + (size_t)(kt*64 + r) * NQKV + q * 8),
                (las_p)((char*)&Ks[0] + (w * 128 + it * 64) * 16),
                16, 0, 0);
        }
    };
    auto stage_v = [&](int kt) {
        #pragma unroll
        for (int it = 0; it < 2; it++) {
            int s = w * 128 + it * 64 + lane;
            int r = s >> 3, qp = s & 7;
            int q = qp ^ (r & 7);
            __builtin_amdgcn_global_load_lds(
                (gas_p)(vb0 + (size_t)r * 2048 + kt*64 + q * 8),
                (las_p)((char*)&Vt[0] + (w * 128 + it * 64) * 16),
                16, 0, 0);
        }
    };

    f32x4 o_acc[2][8];
    const f32x4 zf = {0.f, 0.f, 0.f, 0.f};
    #pragma unroll
    for (int qf = 0; qf < 2; qf++)
        #pragma unroll
        for (int jn = 0; jn < 8; jn++) o_acc[qf][jn] = zf;
    float m_i[2] = {-1e30f, -1e30f}, l_i[2] = {0.f, 0.f};
    int qglob[2] = {q0 + qhalf*32 + l15, q0 + qhalf*32 + 16 + l15};

    stage_k(kt_begin);
    for (int kt = kt_begin; kt < kt_end; kt++) {
        __syncthreads();             // A: K(kt) landed; V buffer free
        stage_v(kt);                 // async during QK+softmax

        f32x4 s_acc[2][4];
        #pragma unroll
        for (int j = 0; j < 4; j++) {
            s_acc[0][j] = zf; s_acc[1][j] = zf;
            #pragma unroll
            for (int k4 = 0; k4 < 4; k4++) {
                bf16x8 ak = *(const bf16x8*)&Ks[koff[j][k4]];
                s_acc[0][j] = __builtin_amdgcn_mfma_f32_16x16x32_bf16(ak, aq[0][k4], s_acc[0][j], 0, 0, 0);
                s_acc[1][j] = __builtin_amdgcn_mfma_f32_16x16x32_bf16(ak, aq[1][k4], s_acc[1][j], 0, 0, 0);
            }
        }

        bf16x8 pp[2][2];
        #pragma unroll
        for (int qf = 0; qf < 2; qf++) {
            float sv[4][4];
            #pragma unroll
            for (int j = 0; j < 4; j++)
                #pragma unroll
                for (int r = 0; r < 4; r++)
                    sv[j][r] = s_acc[qf][j][r];          // Q pre-scaled
            if (kt == qt) {
                #pragma unroll
                for (int j = 0; j < 4; j++)
                    #pragma unroll
                    for (int r = 0; r < 4; r++) {
                        int sloc = ((j >> 1) * 32) + quad*8 + ((j & 1) * 4) + r;
                        if (kt*64 + sloc > qglob[qf]) sv[j][r] = -1e30f;
                    }
            }
            float mx = sv[0][0];
            #pragma unroll
            for (int j = 0; j < 4; j++)
                #pragma unroll
                for (int r = 0; r < 4; r++) mx = fmaxf(mx, sv[j][r]);
            mx = fmaxf(mx, __shfl_xor(mx, 16));
            mx = fmaxf(mx, __shfl_xor(mx, 32));
            int defer = __all(mx <= m_i[qf] + 8.f);
            float mnew = defer ? m_i[qf] : fmaxf(m_i[qf], mx);
            float rs = 0.f;
            float p[4][4];
            #pragma unroll
            for (int j = 0; j < 4; j++)
                #pragma unroll
                for (int r = 0; r < 4; r++) {
                    p[j][r] = __expf(sv[j][r] - mnew);
                    rs += p[j][r];
                }
            if (!defer) {
                float alpha = __expf(m_i[qf] - mnew);
                l_i[qf] *= alpha;
                #pragma unroll
                for (int jn = 0; jn < 8; jn++)
                    #pragma unroll
                    for (int r = 0; r < 4; r++) o_acc[qf][jn][r] *= alpha;
                m_i[qf] = mnew;
            }
            l_i[qf] += rs;
            #pragma unroll
            for (int r = 0; r < 4; r++) {
                pp[qf][0][r]     = (short)f2b(p[0][r]);
                pp[qf][0][r + 4] = (short)f2b(p[1][r]);
                pp[qf][1][r]     = (short)f2b(p[2][r]);
                pp[qf][1][r + 4] = (short)f2b(p[3][r]);
            }
        }

        __syncthreads();             // B: V(kt) landed; K buffer free
        if (kt + 1 < kt_end) stage_k(kt + 1);

        #pragma unroll
        for (int jn = 0; jn < 8; jn++) {
            bf16x8 av0 = *(const bf16x8*)&Vt[jn*1024 + vbase0];
            bf16x8 av1 = *(const bf16x8*)&Vt[jn*1024 + vbase1];
            o_acc[0][jn] = __builtin_amdgcn_mfma_f32_16x16x32_bf16(av0, pp[0][0], o_acc[0][jn], 0, 0, 0);
            o_acc[0][jn] = __builtin_amdgcn_mfma_f32_16x16x32_bf16(av1, pp[0][1], o_acc[0][jn], 0, 0, 0);
            o_acc[1][jn] = __builtin_amdgcn_mfma_f32_16x16x32_bf16(av0, pp[1][0], o_acc[1][jn], 0, 0, 0);
            o_acc[1][jn] = __builtin_amdgcn_mfma_f32_16x16x32_bf16(av1, pp[1][1], o_acc[1][jn], 0, 0, 0);
        }
    }

    int pi = 0, mi = 0;
    if (qt >= 14) {
        if (qt < 28) { mi = (qt - 14) * 2 + c;       pi = qt - 14; }
        else         { mi = 28 + (qt - 28) * 3 + c;  pi = 14 + (qt - 28) * 2 + c; }
    }
    #pragma unroll
    for (int qf = 0; qf < 2; qf++) {
        float lt = l_i[qf];
        lt += __shfl_xor(lt, 16);
        lt += __shfl_xor(lt, 32);
        float inv = 1.f / lt;
        int q_local = qhalf * 32 + qf * 16 + l15;
        unsigned short* dst;
        if (lastc)
            dst = ao + (size_t)(b*2048 + q0 + q_local) * 2048 + h*128;
        else
            dst = wsP + (size_t)(((pi * 8 + hk * 2 + b) * 4 + hw) * 64 + q_local) * 128;
        #pragma unroll
        for (int jn = 0; jn < 8; jn++) {
            ushort4 ov;
            ov.x = f2b(o_acc[qf][jn][0] * inv);
            ov.y = f2b(o_acc[qf][jn][1] * inv);
            ov.z = f2b(o_acc[qf][jn][2] * inv);
            ov.w = f2b(o_acc[qf][jn][3] * inv);
            *(ushort4*)(dst + jn*16 + quad*4) = ov;
        }
        if (qt >= 14 && quad == 0)
            wsML[(mi * 8 + hk * 2 + b) * 256 + hw * 64 + q_local]
                = make_float2(m_i[qf], lt);
    }
}

// ---------- merge split-K partials (rows q >= 896, 2-3 chunks) -------------
__global__ __launch_bounds__(256)
void merge_kernel(unsigned short* __restrict__ ao,
                  const unsigned short* __restrict__ wsP,
                  const float2* __restrict__ wsML) {
    int t = blockIdx.x * 256 + threadIdx.x;
    int d = (t & 15) * 8;
    int h = (t >> 4) & 15;
    int rest = t >> 8;                // 0..2303
    int q_off = rest % 1152;
    int b = rest / 1152;
    int q = 896 + q_off;
    int qt = q >> 6, q_local = q & 63;
    int hk = h >> 2, hw = h & 3;
    int nch = (qt >= 28) ? 3 : 2;

    float mv[3], lv[3];
    for (int cc = 0; cc < nch; cc++) {
        int mi = (qt < 28) ? (qt - 14) * 2 + cc : 28 + (qt - 28) * 3 + cc;
        float2 ml = wsML[(mi * 8 + hk * 2 + b) * 256 + hw * 64 + q_local];
        mv[cc] = ml.x; lv[cc] = ml.y;
    }
    float M = mv[0];
    for (int cc = 1; cc < nch; cc++) M = fmaxf(M, mv[cc]);
    float f[3], S = 0.f;
    for (int cc = 0; cc < nch; cc++) { f[cc] = __expf(mv[cc] - M) * lv[cc]; S += f[cc]; }
    float inv = 1.f / S;

    unsigned short* arow = ao + (size_t)(b*2048 + q) * 2048 + h*128 + d;
    float outv[8];
    {
        ushort4 a0 = *(ushort4*)arow, a1 = *(ushort4*)(arow + 4);
        float fl = f[nch-1];
        outv[0] = fl*b2f(a0.x); outv[1] = fl*b2f(a0.y);
        outv[2] = fl*b2f(a0.z); outv[3] = fl*b2f(a0.w);
        outv[4] = fl*b2f(a1.x); outv[5] = fl*b2f(a1.y);
        outv[6] = fl*b2f(a1.z); outv[7] = fl*b2f(a1.w);
    }
    for (int cc = 0; cc < nch - 1; cc++) {
        int pi = (qt < 28) ? (qt - 14) : 14 + (qt - 28) * 2 + cc;
        const unsigned short* prow =
            wsP + (size_t)(((pi * 8 + hk * 2 + b) * 4 + hw) * 64 + q_local) * 128 + d;
        ushort4 p0 = *(const ushort4*)prow, p1 = *(const ushort4*)(prow + 4);
        float fc = f[cc];
        outv[0] += fc*b2f(p0.x); outv[1] += fc*b2f(p0.y);
        outv[2] += fc*b2f(p0.z); outv[3] += fc*b2f(p0.w);
        outv[4] += fc*b2f(p1.x); outv[5] += fc*b2f(p1.y);
        outv[6] += fc*b2f(p1.z); outv[7] += fc*b2f(p1.w);
    }
    ushort4 o0, o1;
    o0.x = f2b(outv[0]*inv); o0.y = f2b(outv[1]*inv);
    o0.z = f2b(outv[2]*inv); o0.w = f2b(outv[3]*inv);
    o1.x = f2b(outv[4]*inv); o1.y = f2b(outv[5]*inv);
    o1.z = f2b(outv[6]*inv); o1.w = f2b(outv[7]*inv);
    *(ushort4*)arow = o0;
    *(ushort4*)(arow + 4) = o1;
}

// ---------- launch ---------------------------------------------------------
extern "C" void kernel_launch(void* const* d_in, const int* in_sizes, int n_in,
                              void* d_out, int out_size, void* d_ws, size_t ws_size,
                              hipStream_t stream) {
    const float* x     = (const float*)d_in[0];
    const float* freqs = (const float*)d_in[1];
    const float* wq    = (const float*)d_in[2];
    const float* wk    = (const float*)d_in[3];
    const float* wv    = (const float*)d_in[4];
    const float* wo    = (const float*)d_in[5];
    float* out = (float*)d_out;

    char* ws = (char*)d_ws;
    unsigned short* xbf    = (unsigned short*)(ws);                  // 16MB
    unsigned short* aobuf  = (unsigned short*)(ws);                  // alias (xbf dead)
    unsigned short* wqkvT  = (unsigned short*)(ws + (16u<<20));      // 12MB
    unsigned short* woT    = (unsigned short*)(ws + (28u<<20));      // 8MB
    unsigned short* qkvbuf = (unsigned short*)(ws + (36u<<20));      // 24MB
    unsigned short* vTbuf  = (unsigned short*)(ws + (60u<<20));      // 4MB
    unsigned short* wsP  = (unsigned short*)(ws + (16u<<20));        // 11MB (aliases wqkvT, dead)
    float2*         wsML = (float2*)(ws + (16u<<20) + 176u*65536u);  // 640KB

    convert_all<<<dim3(64, 64, 6), dim3(256), 0, stream>>>(
        x, wq, wk, wv, wo, xbf, wqkvT, woT);
    gemm8<<<dim3(16, 16), dim3(512), 0, stream>>>(
        xbf, wqkvT, qkvbuf, vTbuf, freqs);
    attn_mfma<<<dim3(54, 4, 2), dim3(512), 0, stream>>>(qkvbuf, vTbuf, aobuf, wsP, wsML);
    merge_kernel<<<2304, dim3(256), 0, stream>>>(aobuf, wsP, wsML);
    gemm8o<<<dim3(2048/128, M_/256), dim3(512), 0, stream>>>(aobuf, woT, out);
}